// Round 3
// baseline (2062.570 us; speedup 1.0000x reference)
//
#include <hip/hip_runtime.h>
#include <hip/hip_fp16.h>
#include <math.h>

#define B_ 128
#define T_ 256
#define E_ 300
#define H_ 256
#define N5_ 1280
#define NSTEPS 511
#define DMAX 8

typedef _Float16 half2_t __attribute__((ext_vector_type(2)));
typedef _Float16 half8_t __attribute__((ext_vector_type(8)));
typedef float float4_t __attribute__((ext_vector_type(4)));

#if defined(__has_builtin)
# if __has_builtin(__builtin_amdgcn_fdot2)
#  define HAVE_FDOT2 1
# endif
#endif

union U32H2 { unsigned int u; half2_t h; };

__device__ __forceinline__ unsigned int pack2(float a, float b){
  U32H2 v; v.h.x = (_Float16)a; v.h.y = (_Float16)b; return v.u;
}
__device__ __forceinline__ half2_t uh2(unsigned int u){ U32H2 v; v.u = u; return v.h; }

__device__ __forceinline__ float fdot2f(half2_t a, half2_t b, float c){
#ifdef HAVE_FDOT2
  return __builtin_amdgcn_fdot2(a, b, c, false);
#else
  return c + (float)a.x*(float)b.x + (float)a.y*(float)b.y;
#endif
}

__device__ __forceinline__ float sigm(float x){ return 1.f/(1.f + expf(-x)); }

// ---------------------------------------------------------------------------
// K0: pack Wr (fp32, 512x1280):
//  Wl2t[n][k2] = {Wr[2k2][n], Wr[2k2+1][n]}  (n-major, rows 0..255 = hl part)
//  Ostr[q][n]  = uint4 of k2=4q..4q+3 for o-gate col (1024+n)  [coalesced stream]
// ---------------------------------------------------------------------------
__global__ __launch_bounds__(256) void k0_pack(const float* __restrict__ Wr,
    unsigned int* __restrict__ Wl2t, uint4* __restrict__ Ostr){
  int idx = blockIdx.x*256 + threadIdx.x;
  if (idx < 128*N5_){
    int k2 = idx / N5_, n = idx - k2*N5_;
    Wl2t[(size_t)n*128 + k2] = pack2(Wr[(size_t)(2*k2)*N5_ + n], Wr[(size_t)(2*k2+1)*N5_ + n]);
  }
  if (idx < 32*256){
    int q = idx >> 8, n = idx & 255;
    unsigned int u[4];
    #pragma unroll
    for (int j=0;j<4;j++){
      int k2 = q*4 + j;
      u[j] = pack2(Wr[(size_t)(2*k2)*N5_ + 1024 + n], Wr[(size_t)(2*k2+1)*N5_ + 1024 + n]);
    }
    uint4 v; v.x=u[0]; v.y=u[1]; v.z=u[2]; v.w=u[3];
    Ostr[(size_t)q*256 + n] = v;
  }
}

// ---------------------------------------------------------------------------
// K1: fused projection GEMM (unchanged).
// ---------------------------------------------------------------------------
__global__ __launch_bounds__(256) void k1_proj(
    const float* __restrict__ x, const float* __restrict__ Wp, const float* __restrict__ bp,
    const float* __restrict__ Wg, const float* __restrict__ bg,
    _Float16* __restrict__ h2, _Float16* __restrict__ c2){
  __shared__ __align__(16) _Float16 As [64*32];
  __shared__ __align__(16) _Float16 BsP[64*32];
  __shared__ __align__(16) _Float16 BsG[64*32];
  const int tid = threadIdx.x;
  const int row0 = blockIdx.x * 64;
  const int n0   = blockIdx.y * 64;
  const int wave = tid >> 6, lane = tid & 63;
  const int ml = lane & 15, quad = lane >> 4;
  float4_t accP[4], accG[4];
  #pragma unroll
  for (int i=0;i<4;i++){ accP[i]=(float4_t)(0.f); accG[i]=(float4_t)(0.f); }
  const int ar = tid >> 2, ak = (tid & 3) * 8;
  const int bk = tid >> 3, bn = (tid & 7) * 8;
  for (int kk = 0; kk < E_; kk += 32){
    __syncthreads();
    {
      const float* src = x + (size_t)(row0 + ar)*E_ + kk + ak;
      float v[8];
      #pragma unroll
      for (int q=0;q<2;q++){
        if (kk + ak + q*4 + 4 <= E_){
          float4_t f = *(const float4_t*)(src + q*4);
          v[q*4+0]=f.x; v[q*4+1]=f.y; v[q*4+2]=f.z; v[q*4+3]=f.w;
        } else {
          #pragma unroll
          for (int j=0;j<4;j++){ int kg = kk+ak+q*4+j; v[q*4+j] = (kg<E_) ? src[q*4+j] : 0.f; }
        }
      }
      #pragma unroll
      for (int j=0;j<8;j++) As[ar*32 + ak + j] = (_Float16)v[j];
    }
    {
      const int kg = kk + bk;
      if (kg < E_){
        const float* sp_ = Wp + (size_t)kg*H_ + n0 + bn;
        const float* sg_ = Wg + (size_t)kg*H_ + n0 + bn;
        float4_t p0 = *(const float4_t*)sp_, p1 = *(const float4_t*)(sp_+4);
        float4_t g0 = *(const float4_t*)sg_, g1 = *(const float4_t*)(sg_+4);
        float pv[8]={p0.x,p0.y,p0.z,p0.w,p1.x,p1.y,p1.z,p1.w};
        float gv[8]={g0.x,g0.y,g0.z,g0.w,g1.x,g1.y,g1.z,g1.w};
        #pragma unroll
        for (int j=0;j<8;j++){ BsP[(bn+j)*32+bk]=(_Float16)pv[j]; BsG[(bn+j)*32+bk]=(_Float16)gv[j]; }
      } else {
        #pragma unroll
        for (int j=0;j<8;j++){ BsP[(bn+j)*32+bk]=(_Float16)0.f; BsG[(bn+j)*32+bk]=(_Float16)0.f; }
      }
    }
    __syncthreads();
    half8_t a = *(const half8_t*)&As[(wave*16 + ml)*32 + quad*8];
    #pragma unroll
    for (int nt=0; nt<4; nt++){
      half8_t b1 = *(const half8_t*)&BsP[(nt*16 + ml)*32 + quad*8];
      accP[nt] = __builtin_amdgcn_mfma_f32_16x16x32_f16(a, b1, accP[nt], 0,0,0);
      half8_t b2 = *(const half8_t*)&BsG[(nt*16 + ml)*32 + quad*8];
      accG[nt] = __builtin_amdgcn_mfma_f32_16x16x32_f16(a, b2, accG[nt], 0,0,0);
    }
  }
  #pragma unroll
  for (int nt=0; nt<4; nt++){
    #pragma unroll
    for (int r=0;r<4;r++){
      int row = row0 + wave*16 + quad*4 + r;
      int col = n0 + nt*16 + ml;
      float c = accP[nt][r] + bp[col];
      float g = accG[nt][r] + bg[col];
      float h = sigm(g) * tanhf(c);
      size_t o = (size_t)row*H_ + col;
      c2[o] = (_Float16)c;
      h2[o] = (_Float16)h;
    }
  }
}

// ---------------------------------------------------------------------------
// K2: R = h_buf @ Wr[256:512,:] + br -> f16 R2 (unchanged)
// ---------------------------------------------------------------------------
__global__ __launch_bounds__(256) void k2_rproj(
    const _Float16* __restrict__ h2, const float* __restrict__ Wr, const float* __restrict__ br,
    _Float16* __restrict__ R2){
  __shared__ __align__(16) _Float16 As[64*32];
  __shared__ __align__(16) _Float16 Bs[64*32];
  const int tid = threadIdx.x;
  const int row0 = blockIdx.x*64, n0 = blockIdx.y*64;
  const int wave = tid>>6, lane = tid&63, ml = lane&15, quad = lane>>4;
  float4_t acc[4];
  #pragma unroll
  for (int i=0;i<4;i++) acc[i]=(float4_t)(0.f);
  const int ar = tid>>2, ak = (tid&3)*8;
  const int bk = tid>>3, bn = (tid&7)*8;
  for (int kk=0; kk<H_; kk+=32){
    __syncthreads();
    *(half8_t*)&As[ar*32+ak] = *(const half8_t*)(h2 + (size_t)(row0+ar)*H_ + kk + ak);
    {
      const float* src = Wr + (size_t)(256 + kk + bk)*N5_ + n0 + bn;
      float4_t f0 = *(const float4_t*)src, f1 = *(const float4_t*)(src+4);
      float v[8]={f0.x,f0.y,f0.z,f0.w,f1.x,f1.y,f1.z,f1.w};
      #pragma unroll
      for (int j=0;j<8;j++) Bs[(bn+j)*32+bk] = (_Float16)v[j];
    }
    __syncthreads();
    half8_t a = *(const half8_t*)&As[(wave*16+ml)*32 + quad*8];
    #pragma unroll
    for (int nt=0; nt<4; nt++){
      half8_t b8 = *(const half8_t*)&Bs[(nt*16+ml)*32 + quad*8];
      acc[nt] = __builtin_amdgcn_mfma_f32_16x16x32_f16(a, b8, acc[nt], 0,0,0);
    }
  }
  #pragma unroll
  for (int nt=0; nt<4; nt++){
    #pragma unroll
    for (int r=0;r<4;r++){
      int row = row0 + wave*16 + quad*4 + r;
      int col = n0 + nt*16 + ml;
      R2[(size_t)row*N5_ + col] = (_Float16)(acc[nt][r] + br[col]);
    }
  }
}

// ---------------------------------------------------------------------------
// K3 v3: weight-resident scan with guaranteed scalarization.
//  - 96 NAMED uint4 vars (wA_q/wB_q/wC_q) = gates i,fl,fr -> SSA values,
//    allocator uses VGPR+AGPR (cheap accvgpr copies), never scratch.
//  - gate g in LDS (256 x 33 uint4, padded), gate o streamed coalesced from
//    Ostr [chunk][thread] with distance-2 group pipeline.
//  - trans preloaded to LDS; depth-1 prefetch of R2 rows (during the shift
//    that defines the tag) and of h2/c2 (during the step before a shift).
// LDS layout (bytes):
//   [0,135168)        wlds4  256 x 33 uint4 (g-gate)
//   [135168,143360)   sh_    float[DMAX][256]
//   [143360,151552)   sc_    float[DMAX][256]
//   [151552,152064)   hl2    uint[128]
//   [152064,152096)   tags   int[DMAX]
//   [152096,154144)   trs    int[512]
// ---------------------------------------------------------------------------
#define K3_LDS_BYTES 154144

#define CHUNKS(X) X(0) X(1) X(2) X(3) X(4) X(5) X(6) X(7) X(8) X(9) X(10) X(11) \
  X(12) X(13) X(14) X(15) X(16) X(17) X(18) X(19) X(20) X(21) X(22) X(23) \
  X(24) X(25) X(26) X(27) X(28) X(29) X(30) X(31)

#define DOT4(hh4, ww4, acc) do{ \
  acc = fdot2f(uh2((hh4).x), uh2((ww4).x), acc); \
  acc = fdot2f(uh2((hh4).y), uh2((ww4).y), acc); \
  acc = fdot2f(uh2((hh4).z), uh2((ww4).z), acc); \
  acc = fdot2f(uh2((hh4).w), uh2((ww4).w), acc); }while(0)

#define DOCHUNK(q, WO) { uint4 hv = hl4[q]; uint4 wg = wlds4[wbase + q]; \
  DOT4(hv, wA_##q, a0); DOT4(hv, wB_##q, a1); DOT4(hv, wC_##q, a2); \
  DOT4(hv, wg, a3); DOT4(hv, WO, a4); }

#define ISSUE4(SI, gi) { SI[0]=so4[((gi)*4+0)*256]; SI[1]=so4[((gi)*4+1)*256]; \
                         SI[2]=so4[((gi)*4+2)*256]; SI[3]=so4[((gi)*4+3)*256]; }

#define DOGROUP(q0,q1,q2,q3, SU) \
  DOCHUNK(q0, SU[0]) DOCHUNK(q1, SU[1]) DOCHUNK(q2, SU[2]) DOCHUNK(q3, SU[3])

__global__ __launch_bounds__(256, 1) void k3_scan(
    const int* __restrict__ trans, const _Float16* __restrict__ h2, const _Float16* __restrict__ c2,
    const _Float16* __restrict__ R2, const unsigned int* __restrict__ Wl2t,
    const uint4* __restrict__ Ostr, const float* __restrict__ Wr,
    const float* __restrict__ br, float* __restrict__ out){
  extern __shared__ char smem[];
  uint4* wlds4        = (uint4*)smem;
  float* sh_          = (float*)(smem + 135168);
  float* sc_          = (float*)(smem + 143360);
  unsigned int* hl2   = (unsigned int*)(smem + 151552);
  int* tags           = (int*)(smem + 152064);
  int* trs            = (int*)(smem + 152096);
  const uint4* hl4    = (const uint4*)hl2;

  const int b = blockIdx.x, tid = threadIdx.x;
  const int wbase = tid*33;

  // --- named resident weights (gates i, fl, fr) — 96 SSA uint4 values
  #define DECLW(q) uint4 wA_##q, wB_##q, wC_##q;
  CHUNKS(DECLW)
  #undef DECLW
  {
    const uint4* srcA = (const uint4*)(Wl2t + (size_t)(      tid)*128);
    const uint4* srcB = (const uint4*)(Wl2t + (size_t)(256 + tid)*128);
    const uint4* srcC = (const uint4*)(Wl2t + (size_t)(512 + tid)*128);
    #define LOADW(q) wA_##q = srcA[q]; wB_##q = srcB[q]; wC_##q = srcC[q];
    CHUNKS(LOADW)
    #undef LOADW
  }
  { // g-gate col -> LDS (padded rows of 33 uint4)
    const uint4* sg = (const uint4*)(Wl2t + (size_t)(768 + tid)*128);
    #pragma unroll
    for (int g=0; g<32; g++) wlds4[wbase + g] = sg[g];
  }
  const uint4* so4 = Ostr + tid;   // o-gate stream, coalesced [chunk][thread]

  // trans -> LDS
  trs[tid] = (tid < NSTEPS) ? trans[(size_t)tid*B_ + b] : 1;
  { int j = 256 + tid; if (j < NSTEPS) trs[j] = trans[(size_t)j*B_ + b]; }

  #pragma unroll
  for (int d=0; d<DMAX; d++){ sh_[d*H_+tid]=0.f; sc_[d*H_+tid]=0.f; }
  if (tid < DMAX) tags[tid] = -1;
  __syncthreads();

  int sp = 0, bptr = T_;
  // prefetch registers (stale-safe: compared by tag/src at use; arrays const)
  int pf_tag = -1, pf_src = -1;
  _Float16 pA=(_Float16)0.f, pB=(_Float16)0.f, pC=(_Float16)0.f, pD=(_Float16)0.f, pE=(_Float16)0.f;
  _Float16 ph=(_Float16)0.f, pc_=(_Float16)0.f;

  for (int step=0; step<NSTEPS; step++){
    __syncthreads();
    const int tr = trs[step];
    int just_src = -1;
    if (tr == 0){                          // ---- SHIFT
      const int nbp = bptr - 1;
      const int src = nbp > 0 ? nbp : 0;
      int slot = sp < 0 ? 0 : (sp > DMAX-1 ? DMAX-1 : sp);
      _Float16 hv_, cv_;
      if (src == pf_src){ hv_ = ph; cv_ = pc_; }
      else { const size_t o = ((size_t)b*T_ + src)*H_ + tid; hv_ = h2[o]; cv_ = c2[o]; }
      sh_[slot*H_+tid] = (float)hv_;
      sc_[slot*H_+tid] = (float)cv_;
      if (tid == 0) tags[slot] = src;
      sp += 1; bptr = nbp; just_src = src;
    } else {                               // ---- REDUCE
      int ir = sp-1 > 0 ? sp-1 : 0;
      int il = sp-2 > 0 ? sp-2 : 0;
      ir = ir > DMAX-1 ? DMAX-1 : ir;
      il = il > DMAX-1 ? DMAX-1 : il;
      if (tid < H_/2) hl2[tid] = pack2(sh_[il*H_+2*tid], sh_[il*H_+2*tid+1]);
      const int tg   = tags[ir];
      const float cl = sc_[il*H_+tid];
      const float cr = sc_[ir*H_+tid];
      __syncthreads();
      float a0,a1,a2,a3,a4;
      if (tg >= 0 && tg == pf_tag){
        a0=(float)pA; a1=(float)pB; a2=(float)pC; a3=(float)pD; a4=(float)pE;
      } else if (tg >= 0){
        const _Float16* rr = R2 + ((size_t)b*T_ + tg)*N5_ + tid;
        a0=(float)rr[0]; a1=(float)rr[256]; a2=(float)rr[512]; a3=(float)rr[768]; a4=(float)rr[1024];
      } else {
        a0=br[tid]; a1=br[tid+256]; a2=br[tid+512]; a3=br[tid+768]; a4=br[tid+1024];
      }
      // main dot: resident + LDS + pipelined coalesced stream
      {
        uint4 s0[4], s1[4], s2[4];
        ISSUE4(s0,0) ISSUE4(s1,1)
        ISSUE4(s2,2) DOGROUP(0,1,2,3,     s0)
        ISSUE4(s0,3) DOGROUP(4,5,6,7,     s1)
        ISSUE4(s1,4) DOGROUP(8,9,10,11,   s2)
        ISSUE4(s2,5) DOGROUP(12,13,14,15, s0)
        ISSUE4(s0,6) DOGROUP(16,17,18,19, s1)
        ISSUE4(s1,7) DOGROUP(20,21,22,23, s2)
        DOGROUP(24,25,26,27, s0)
        DOGROUP(28,29,30,31, s1)
      }
      if (tg < 0){                         // cold general fallback: direct fp32 Wr
        for (int k=0; k<H_; k++){
          const float hrk = sh_[ir*H_+k];
          const float* wr = Wr + (size_t)(256+k)*N5_ + tid;
          a0 += hrk*wr[0]; a1 += hrk*wr[256]; a2 += hrk*wr[512];
          a3 += hrk*wr[768]; a4 += hrk*wr[1024];
        }
      }
      const float cnew = sigm(a1)*cl + sigm(a2)*cr + sigm(a0)*tanhf(a3);
      const float hnew = sigm(a4)*tanhf(cnew);
      sh_[il*H_+tid] = hnew;
      sc_[il*H_+tid] = cnew;
      if (tid == 0) tags[il] = -1;
      sp -= 1;
    }
    // ---- depth-1 prefetch for the NEXT step (addresses are trans-determined)
    if (step+1 < NSTEPS){
      const int ntr = trs[step+1];
      if (ntr == 0){
        int ns = bptr - 1; if (ns < 0) ns = 0;
        const size_t o = ((size_t)b*T_ + ns)*H_ + tid;
        ph = h2[o]; pc_ = c2[o]; pf_src = ns;
      } else if (just_src >= 0){
        const _Float16* rr = R2 + ((size_t)b*T_ + just_src)*N5_ + tid;
        pA=rr[0]; pB=rr[256]; pC=rr[512]; pD=rr[768]; pE=rr[1024];
        pf_tag = just_src;
      }
    }
  }
  __syncthreads();
  int fs = sp-1 > 0 ? sp-1 : 0;
  fs = fs > DMAX-1 ? DMAX-1 : fs;
  out[(size_t)b*H_ + tid] = sh_[fs*H_+tid];
}

// ---------------------------------------------------------------------------
// Workspace layout (bytes):
//   h2   @ 0          : 16,777,216
//   c2   @ 16777216   : 16,777,216
//   R2   @ 33554432   : 83,886,080
//   Wl2t @ 117440512  : 655,360
//   Ostr @ 118095872  : 131,072   (total 118,226,944 — within proven footprint)
// ---------------------------------------------------------------------------
extern "C" void kernel_launch(void* const* d_in, const int* in_sizes, int n_in,
                              void* d_out, int out_size, void* d_ws, size_t ws_size,
                              hipStream_t stream){
  const float* x    = (const float*)d_in[0];
  const int*   trn  = (const int*)  d_in[1];
  const float* Wp   = (const float*)d_in[2];
  const float* bp   = (const float*)d_in[3];
  const float* Wg   = (const float*)d_in[4];
  const float* bg   = (const float*)d_in[5];
  const float* Wr   = (const float*)d_in[6];
  const float* br   = (const float*)d_in[7];
  float* out = (float*)d_out;
  char* w = (char*)d_ws;
  _Float16* h2 = (_Float16*)(w);
  _Float16* c2 = (_Float16*)(w + (size_t)16777216);
  _Float16* R2 = (_Float16*)(w + (size_t)33554432);
  unsigned int* Wl2t = (unsigned int*)(w + (size_t)117440512);
  uint4* Ostr        = (uint4*)(w + (size_t)118095872);

  hipLaunchKernelGGL(k0_pack,  dim3(640),     dim3(256), 0, stream, Wr, Wl2t, Ostr);
  hipLaunchKernelGGL(k1_proj,  dim3(512, 4),  dim3(256), 0, stream, x, Wp, bp, Wg, bg, h2, c2);
  hipLaunchKernelGGL(k2_rproj, dim3(512, 20), dim3(256), 0, stream, h2, Wr, br, R2);
  hipLaunchKernelGGL(k3_scan,  dim3(128),     dim3(256), K3_LDS_BYTES, stream, trn, h2, c2, R2, Wl2t, Ostr, Wr, br, out);
}

// Round 4
// 1256.139 us; speedup vs baseline: 1.6420x; 1.6420x over previous
//
#include <hip/hip_runtime.h>
#include <hip/hip_fp16.h>
#include <math.h>

#define B_ 128
#define T_ 256
#define E_ 300
#define H_ 256
#define N5_ 1280
#define NSTEPS 511
#define DMAX 8

typedef _Float16 half2_t __attribute__((ext_vector_type(2)));
typedef _Float16 half8_t __attribute__((ext_vector_type(8)));
typedef float float4_t __attribute__((ext_vector_type(4)));

#if defined(__has_builtin)
# if __has_builtin(__builtin_amdgcn_fdot2)
#  define HAVE_FDOT2 1
# endif
# if __has_builtin(__builtin_amdgcn_sdot4)
#  define HAVE_SDOT4 1
# endif
#endif

union U32H2 { unsigned int u; half2_t h; };
__device__ __forceinline__ unsigned int pack2(float a, float b){
  U32H2 v; v.h.x = (_Float16)a; v.h.y = (_Float16)b; return v.u;
}
__device__ __forceinline__ float sigm(float x){ return 1.f/(1.f + expf(-x)); }

__device__ __forceinline__ int sdot4i(int a, int b, int c){
#ifdef HAVE_SDOT4
  return __builtin_amdgcn_sdot4(a, b, c, false);
#else
  return c + (int)(signed char)(a)     * (int)(signed char)(b)
           + (int)(signed char)(a>>8)  * (int)(signed char)(b>>8)
           + (int)(signed char)(a>>16) * (int)(signed char)(b>>16)
           + (int)(signed char)(a>>24) * (int)(signed char)(b>>24);
#endif
}
__device__ __forceinline__ int dot16(uint4 h, uint4 w, int acc){
  acc = sdot4i((int)h.x, (int)w.x, acc);
  acc = sdot4i((int)h.y, (int)w.y, acc);
  acc = sdot4i((int)h.z, (int)w.z, acc);
  acc = sdot4i((int)h.w, (int)w.w, acc);
  return acc;
}

// ---------------------------------------------------------------------------
// K0a: per-column absmax scale for the hl-part of Wr (rows 0..255).
// grid 1280 blocks x 64 thr; scales[n] = max_k |Wr[k][n]| / 127.
// ---------------------------------------------------------------------------
__global__ __launch_bounds__(64) void k0a_scale(const float* __restrict__ Wr,
    float* __restrict__ scales){
  const int n = blockIdx.x, t = threadIdx.x;
  float m = 0.f;
  #pragma unroll
  for (int j=0;j<4;j++) m = fmaxf(m, fabsf(Wr[(size_t)(t+64*j)*N5_ + n]));
  #pragma unroll
  for (int off=32; off; off>>=1) m = fmaxf(m, __shfl_xor(m, off, 64));
  if (t==0) scales[n] = fmaxf(m, 1e-20f) * (1.f/127.f);
}

// ---------------------------------------------------------------------------
// K0b: quantize hl-part of Wr to int8 uint4-planes:
//   W4[((g*16 + c4)*256 + n')] = bytes k=16*c4 .. 16*c4+15 of column (256g+n')
// 20480 uint4 total (5 gates x 16 planes x 256 cols) = 320 KB.
// ---------------------------------------------------------------------------
__global__ __launch_bounds__(256) void k0b_quant(const float* __restrict__ Wr,
    const float* __restrict__ scales, uint4* __restrict__ W4){
  int idx = blockIdx.x*256 + threadIdx.x;          // 0..20479
  if (idx >= 20480) return;
  const int g  = idx >> 12;          // /4096
  const int r  = idx & 4095;
  const int c4 = r >> 8;
  const int np = r & 255;
  const int col = g*256 + np;
  const float inv = 1.f / scales[col];
  unsigned int d[4];
  #pragma unroll
  for (int dd=0; dd<4; dd++){
    unsigned int acc = 0;
    #pragma unroll
    for (int j=0;j<4;j++){
      const int k = 16*c4 + 4*dd + j;
      float w = Wr[(size_t)k*N5_ + col];
      int q = (int)rintf(w * inv);
      q = q > 127 ? 127 : (q < -127 ? -127 : q);
      acc |= ((unsigned int)(q & 255)) << (8*j);
    }
    d[dd] = acc;
  }
  uint4 v; v.x=d[0]; v.y=d[1]; v.z=d[2]; v.w=d[3];
  W4[idx] = v;
}

// ---------------------------------------------------------------------------
// K1: fused projection GEMM (unchanged).
// ---------------------------------------------------------------------------
__global__ __launch_bounds__(256) void k1_proj(
    const float* __restrict__ x, const float* __restrict__ Wp, const float* __restrict__ bp,
    const float* __restrict__ Wg, const float* __restrict__ bg,
    _Float16* __restrict__ h2, _Float16* __restrict__ c2){
  __shared__ __align__(16) _Float16 As [64*32];
  __shared__ __align__(16) _Float16 BsP[64*32];
  __shared__ __align__(16) _Float16 BsG[64*32];
  const int tid = threadIdx.x;
  const int row0 = blockIdx.x * 64;
  const int n0   = blockIdx.y * 64;
  const int wave = tid >> 6, lane = tid & 63;
  const int ml = lane & 15, quad = lane >> 4;
  float4_t accP[4], accG[4];
  #pragma unroll
  for (int i=0;i<4;i++){ accP[i]=(float4_t)(0.f); accG[i]=(float4_t)(0.f); }
  const int ar = tid >> 2, ak = (tid & 3) * 8;
  const int bk = tid >> 3, bn = (tid & 7) * 8;
  for (int kk = 0; kk < E_; kk += 32){
    __syncthreads();
    {
      const float* src = x + (size_t)(row0 + ar)*E_ + kk + ak;
      float v[8];
      #pragma unroll
      for (int q=0;q<2;q++){
        if (kk + ak + q*4 + 4 <= E_){
          float4_t f = *(const float4_t*)(src + q*4);
          v[q*4+0]=f.x; v[q*4+1]=f.y; v[q*4+2]=f.z; v[q*4+3]=f.w;
        } else {
          #pragma unroll
          for (int j=0;j<4;j++){ int kg = kk+ak+q*4+j; v[q*4+j] = (kg<E_) ? src[q*4+j] : 0.f; }
        }
      }
      #pragma unroll
      for (int j=0;j<8;j++) As[ar*32 + ak + j] = (_Float16)v[j];
    }
    {
      const int kg = kk + bk;
      if (kg < E_){
        const float* sp_ = Wp + (size_t)kg*H_ + n0 + bn;
        const float* sg_ = Wg + (size_t)kg*H_ + n0 + bn;
        float4_t p0 = *(const float4_t*)sp_, p1 = *(const float4_t*)(sp_+4);
        float4_t g0 = *(const float4_t*)sg_, g1 = *(const float4_t*)(sg_+4);
        float pv[8]={p0.x,p0.y,p0.z,p0.w,p1.x,p1.y,p1.z,p1.w};
        float gv[8]={g0.x,g0.y,g0.z,g0.w,g1.x,g1.y,g1.z,g1.w};
        #pragma unroll
        for (int j=0;j<8;j++){ BsP[(bn+j)*32+bk]=(_Float16)pv[j]; BsG[(bn+j)*32+bk]=(_Float16)gv[j]; }
      } else {
        #pragma unroll
        for (int j=0;j<8;j++){ BsP[(bn+j)*32+bk]=(_Float16)0.f; BsG[(bn+j)*32+bk]=(_Float16)0.f; }
      }
    }
    __syncthreads();
    half8_t a = *(const half8_t*)&As[(wave*16 + ml)*32 + quad*8];
    #pragma unroll
    for (int nt=0; nt<4; nt++){
      half8_t b1 = *(const half8_t*)&BsP[(nt*16 + ml)*32 + quad*8];
      accP[nt] = __builtin_amdgcn_mfma_f32_16x16x32_f16(a, b1, accP[nt], 0,0,0);
      half8_t b2 = *(const half8_t*)&BsG[(nt*16 + ml)*32 + quad*8];
      accG[nt] = __builtin_amdgcn_mfma_f32_16x16x32_f16(a, b2, accG[nt], 0,0,0);
    }
  }
  #pragma unroll
  for (int nt=0; nt<4; nt++){
    #pragma unroll
    for (int r=0;r<4;r++){
      int row = row0 + wave*16 + quad*4 + r;
      int col = n0 + nt*16 + ml;
      float c = accP[nt][r] + bp[col];
      float g = accG[nt][r] + bg[col];
      float h = sigm(g) * tanhf(c);
      size_t o = (size_t)row*H_ + col;
      c2[o] = (_Float16)c;
      h2[o] = (_Float16)h;
    }
  }
}

// ---------------------------------------------------------------------------
// K2: R = h_buf @ Wr[256:512,:] + br -> f16 R2 (unchanged)
// ---------------------------------------------------------------------------
__global__ __launch_bounds__(256) void k2_rproj(
    const _Float16* __restrict__ h2, const float* __restrict__ Wr, const float* __restrict__ br,
    _Float16* __restrict__ R2){
  __shared__ __align__(16) _Float16 As[64*32];
  __shared__ __align__(16) _Float16 Bs[64*32];
  const int tid = threadIdx.x;
  const int row0 = blockIdx.x*64, n0 = blockIdx.y*64;
  const int wave = tid>>6, lane = tid&63, ml = lane&15, quad = lane>>4;
  float4_t acc[4];
  #pragma unroll
  for (int i=0;i<4;i++) acc[i]=(float4_t)(0.f);
  const int ar = tid>>2, ak = (tid&3)*8;
  const int bk = tid>>3, bn = (tid&7)*8;
  for (int kk=0; kk<H_; kk+=32){
    __syncthreads();
    *(half8_t*)&As[ar*32+ak] = *(const half8_t*)(h2 + (size_t)(row0+ar)*H_ + kk + ak);
    {
      const float* src = Wr + (size_t)(256 + kk + bk)*N5_ + n0 + bn;
      float4_t f0 = *(const float4_t*)src, f1 = *(const float4_t*)(src+4);
      float v[8]={f0.x,f0.y,f0.z,f0.w,f1.x,f1.y,f1.z,f1.w};
      #pragma unroll
      for (int j=0;j<8;j++) Bs[(bn+j)*32+bk] = (_Float16)v[j];
    }
    __syncthreads();
    half8_t a = *(const half8_t*)&As[(wave*16+ml)*32 + quad*8];
    #pragma unroll
    for (int nt=0; nt<4; nt++){
      half8_t b8 = *(const half8_t*)&Bs[(nt*16+ml)*32 + quad*8];
      acc[nt] = __builtin_amdgcn_mfma_f32_16x16x32_f16(a, b8, acc[nt], 0,0,0);
    }
  }
  #pragma unroll
  for (int nt=0; nt<4; nt++){
    #pragma unroll
    for (int r=0;r<4;r++){
      int row = row0 + wave*16 + quad*4 + r;
      int col = n0 + nt*16 + ml;
      R2[(size_t)row*N5_ + col] = (_Float16)(acc[nt][r] + br[col]);
    }
  }
}

// ---------------------------------------------------------------------------
// K3 v4: int8 weight-resident scan. One block (256 thr) per batch.
// Thread tid owns output cols {tid, tid+256, ..., tid+1024} (gates i,fl,fr,g,o).
//   i,fl,fr : VGPR  (48 named uint4 = 192 regs, int8, loaded once)
//   g       : LDS   (uint4 planes [16][256], 64 KB, stride-1 b128 reads)
//   o       : L1/L2 stream (64 KB/step, constant addr, 4-ahead pipeline)
// hl quantized to int8 each reduce (|h|<1 -> fixed scale 1/127);
// dot via v_dot4_i32_i8 (320/thread/step); gate = R2row + scf_g * idot.
// LDS layout (bytes):
//   [0,65536)       wgl   uint4[16*256] (g-gate planes)
//   [65536,73728)   sh_   float[8][256]
//   [73728,81920)   sc_   float[8][256]
//   [81920,82176)   hli   uint[64]  (int8-packed hl)
//   [82176,82208)   tags  int[8]
//   [82208,84256)   trs   int[512]
// ---------------------------------------------------------------------------
#define K3_LDS_BYTES 84256

#define C16(X) X(0) X(1) X(2) X(3) X(4) X(5) X(6) X(7) X(8) X(9) X(10) X(11) \
  X(12) X(13) X(14) X(15)

#define DOCHUNK(c, OV) { uint4 hv = hli4[c]; \
  d0 = dot16(hv, wi##c, d0); d1 = dot16(hv, wf##c, d1); d2 = dot16(hv, wx##c, d2); \
  uint4 gv = wgl[(c)*256 + tid]; d3 = dot16(hv, gv, d3); \
  d4 = dot16(hv, OV, d4); }

__global__ __launch_bounds__(256, 1) void k3_scan(
    const int* __restrict__ trans, const _Float16* __restrict__ h2, const _Float16* __restrict__ c2,
    const _Float16* __restrict__ R2, const uint4* __restrict__ W4,
    const float* __restrict__ scales, const float* __restrict__ Wr,
    const float* __restrict__ br, float* __restrict__ out){
  extern __shared__ char smem[];
  uint4* wgl          = (uint4*)smem;
  float* sh_          = (float*)(smem + 65536);
  float* sc_          = (float*)(smem + 73728);
  unsigned int* hli   = (unsigned int*)(smem + 81920);
  int* tags           = (int*)(smem + 82176);
  int* trs            = (int*)(smem + 82208);
  const uint4* hli4   = (const uint4*)hli;

  const int b = blockIdx.x, tid = threadIdx.x;

  // --- prologue: resident int8 weights, gates i(0), fl(1), fr(2)
  #define DECLW(c) uint4 wi##c, wf##c, wx##c;
  C16(DECLW)
  #undef DECLW
  {
    const uint4* P0 = W4 +  0*256 + tid;
    const uint4* P1 = W4 + 16*256 + tid;
    const uint4* P2 = W4 + 32*256 + tid;
    #define LOADW(c) wi##c = P0[(c)*256]; wf##c = P1[(c)*256]; wx##c = P2[(c)*256];
    C16(LOADW)
    #undef LOADW
  }
  { // g-gate planes -> LDS (same layout, coalesced both sides)
    const uint4* P3 = W4 + 48*256 + tid;
    #pragma unroll
    for (int c=0;c<16;c++) wgl[c*256 + tid] = P3[c*256];
  }
  const uint4* oP = W4 + 64*256 + tid;   // o-gate stream base

  // per-thread gate scales (fold 1/127 h-scale)
  const float scf0 = scales[tid       ] * (1.f/127.f);
  const float scf1 = scales[tid +  256] * (1.f/127.f);
  const float scf2 = scales[tid +  512] * (1.f/127.f);
  const float scf3 = scales[tid +  768] * (1.f/127.f);
  const float scf4 = scales[tid + 1024] * (1.f/127.f);

  trs[tid] = (tid < NSTEPS) ? trans[(size_t)tid*B_ + b] : 1;
  { int j = 256 + tid; if (j < NSTEPS) trs[j] = trans[(size_t)j*B_ + b]; }
  #pragma unroll
  for (int d=0; d<DMAX; d++){ sh_[d*H_+tid]=0.f; sc_[d*H_+tid]=0.f; }
  if (tid < DMAX) tags[tid] = -1;
  __syncthreads();

  int sp = 0, bptr = T_;
  int pf_tag = -1, pf_src = -1;
  _Float16 pA=(_Float16)0.f, pB=(_Float16)0.f, pC=(_Float16)0.f, pD=(_Float16)0.f, pE=(_Float16)0.f;
  _Float16 ph=(_Float16)0.f, pc_=(_Float16)0.f;

  for (int step=0; step<NSTEPS; step++){
    __syncthreads();
    const int tr = trs[step];
    int just_src = -1;
    if (tr == 0){                          // ---- SHIFT
      const int nbp = bptr - 1;
      const int src = nbp > 0 ? nbp : 0;
      int slot = sp < 0 ? 0 : (sp > DMAX-1 ? DMAX-1 : sp);
      _Float16 hv_, cv_;
      if (src == pf_src){ hv_ = ph; cv_ = pc_; }
      else { const size_t o = ((size_t)b*T_ + src)*H_ + tid; hv_ = h2[o]; cv_ = c2[o]; }
      sh_[slot*H_+tid] = (float)hv_;
      sc_[slot*H_+tid] = (float)cv_;
      if (tid == 0) tags[slot] = src;
      sp += 1; bptr = nbp; just_src = src;
    } else {                               // ---- REDUCE
      int ir = sp-1 > 0 ? sp-1 : 0;
      int il = sp-2 > 0 ? sp-2 : 0;
      ir = ir > DMAX-1 ? DMAX-1 : ir;
      il = il > DMAX-1 ? DMAX-1 : il;
      if (tid < 64){                       // pack hl -> int8 (|h|<1 guaranteed)
        const float* hp = &sh_[il*H_ + tid*4];
        int q0 = (int)rintf(hp[0]*127.f), q1 = (int)rintf(hp[1]*127.f);
        int q2 = (int)rintf(hp[2]*127.f), q3 = (int)rintf(hp[3]*127.f);
        hli[tid] = (unsigned int)((q0&255) | ((q1&255)<<8) | ((q2&255)<<16) | ((q3&255)<<24));
      }
      const int tg   = tags[ir];
      const float cl = sc_[il*H_+tid];
      const float cr = sc_[ir*H_+tid];
      __syncthreads();
      float a0,a1,a2,a3,a4;
      if (tg >= 0 && tg == pf_tag){
        a0=(float)pA; a1=(float)pB; a2=(float)pC; a3=(float)pD; a4=(float)pE;
      } else if (tg >= 0){
        const _Float16* rr = R2 + ((size_t)b*T_ + tg)*N5_ + tid;
        a0=(float)rr[0]; a1=(float)rr[256]; a2=(float)rr[512]; a3=(float)rr[768]; a4=(float)rr[1024];
      } else {
        a0=br[tid]; a1=br[tid+256]; a2=br[tid+512]; a3=br[tid+768]; a4=br[tid+1024];
      }
      int d0=0,d1=0,d2=0,d3=0,d4=0;
      {
        uint4 o0=oP[0*256], o1=oP[1*256], o2=oP[2*256], o3=oP[3*256];
        DOCHUNK(0,o0)  o0=oP[ 4*256];
        DOCHUNK(1,o1)  o1=oP[ 5*256];
        DOCHUNK(2,o2)  o2=oP[ 6*256];
        DOCHUNK(3,o3)  o3=oP[ 7*256];
        DOCHUNK(4,o0)  o0=oP[ 8*256];
        DOCHUNK(5,o1)  o1=oP[ 9*256];
        DOCHUNK(6,o2)  o2=oP[10*256];
        DOCHUNK(7,o3)  o3=oP[11*256];
        DOCHUNK(8,o0)  o0=oP[12*256];
        DOCHUNK(9,o1)  o1=oP[13*256];
        DOCHUNK(10,o2) o2=oP[14*256];
        DOCHUNK(11,o3) o3=oP[15*256];
        DOCHUNK(12,o0)
        DOCHUNK(13,o1)
        DOCHUNK(14,o2)
        DOCHUNK(15,o3)
      }
      a0 += scf0*(float)d0; a1 += scf1*(float)d1; a2 += scf2*(float)d2;
      a3 += scf3*(float)d3; a4 += scf4*(float)d4;
      if (tg < 0){                         // cold general fallback: direct fp32 Wr
        for (int k=0; k<H_; k++){
          const float hrk = sh_[ir*H_+k];
          const float* wr = Wr + (size_t)(256+k)*N5_ + tid;
          a0 += hrk*wr[0]; a1 += hrk*wr[256]; a2 += hrk*wr[512];
          a3 += hrk*wr[768]; a4 += hrk*wr[1024];
        }
        __syncthreads();                   // tg is block-uniform -> safe
      }
      const float cnew = sigm(a1)*cl + sigm(a2)*cr + sigm(a0)*tanhf(a3);
      const float hnew = sigm(a4)*tanhf(cnew);
      sh_[il*H_+tid] = hnew;
      sc_[il*H_+tid] = cnew;
      if (tid == 0) tags[il] = -1;
      sp -= 1;
    }
    // ---- depth-1 prefetch for the NEXT step
    if (step+1 < NSTEPS){
      const int ntr = trs[step+1];
      if (ntr == 0){
        int ns = bptr - 1; if (ns < 0) ns = 0;
        const size_t o = ((size_t)b*T_ + ns)*H_ + tid;
        ph = h2[o]; pc_ = c2[o]; pf_src = ns;
      } else if (just_src >= 0){
        const _Float16* rr = R2 + ((size_t)b*T_ + just_src)*N5_ + tid;
        pA=rr[0]; pB=rr[256]; pC=rr[512]; pD=rr[768]; pE=rr[1024];
        pf_tag = just_src;
      }
    }
  }
  __syncthreads();
  int fs = sp-1 > 0 ? sp-1 : 0;
  fs = fs > DMAX-1 ? DMAX-1 : fs;
  out[(size_t)b*H_ + tid] = sh_[fs*H_+tid];
}

// ---------------------------------------------------------------------------
// Workspace layout (bytes):
//   h2     @ 0          : 16,777,216
//   c2     @ 16777216   : 16,777,216
//   R2     @ 33554432   : 83,886,080
//   W4     @ 117440512  : 327,680   (int8 uint4-planes, 5 gates)
//   scales @ 117768192  : 5,120     (total 117,773,312 — within proven 118.2 MB)
// ---------------------------------------------------------------------------
extern "C" void kernel_launch(void* const* d_in, const int* in_sizes, int n_in,
                              void* d_out, int out_size, void* d_ws, size_t ws_size,
                              hipStream_t stream){
  const float* x    = (const float*)d_in[0];
  const int*   trn  = (const int*)  d_in[1];
  const float* Wp   = (const float*)d_in[2];
  const float* bp   = (const float*)d_in[3];
  const float* Wg   = (const float*)d_in[4];
  const float* bg   = (const float*)d_in[5];
  const float* Wr   = (const float*)d_in[6];
  const float* br   = (const float*)d_in[7];
  float* out = (float*)d_out;
  char* w = (char*)d_ws;
  _Float16* h2   = (_Float16*)(w);
  _Float16* c2   = (_Float16*)(w + (size_t)16777216);
  _Float16* R2   = (_Float16*)(w + (size_t)33554432);
  uint4*    W4   = (uint4*)   (w + (size_t)117440512);
  float*    scl  = (float*)   (w + (size_t)117768192);

  hipLaunchKernelGGL(k0a_scale, dim3(1280),    dim3(64),  0, stream, Wr, scl);
  hipLaunchKernelGGL(k0b_quant, dim3(80),      dim3(256), 0, stream, Wr, scl, W4);
  hipLaunchKernelGGL(k1_proj,   dim3(512, 4),  dim3(256), 0, stream, x, Wp, bp, Wg, bg, h2, c2);
  hipLaunchKernelGGL(k2_rproj,  dim3(512, 20), dim3(256), 0, stream, h2, Wr, br, R2);
  hipLaunchKernelGGL(k3_scan,   dim3(128),     dim3(256), K3_LDS_BYTES, stream, trn, h2, c2, R2, W4, scl, Wr, br, out);
}

// Round 5
// 1003.932 us; speedup vs baseline: 2.0545x; 1.2512x over previous
//
#include <hip/hip_runtime.h>
#include <hip/hip_fp16.h>
#include <math.h>

#define B_ 128
#define T_ 256
#define E_ 300
#define H_ 256
#define N5_ 1280
#define NSTEPS 511
#define DMAX 8

typedef _Float16 half2_t __attribute__((ext_vector_type(2)));
typedef _Float16 half8_t __attribute__((ext_vector_type(8)));
typedef float float4_t __attribute__((ext_vector_type(4)));

#if defined(__has_builtin)
# if __has_builtin(__builtin_amdgcn_sdot4)
#  define HAVE_SDOT4 1
# endif
#endif

union U32H2 { unsigned int u; half2_t h; };
__device__ __forceinline__ float sigm(float x){ return 1.f/(1.f + expf(-x)); }

__device__ __forceinline__ int sdot4i(int a, int b, int c){
#ifdef HAVE_SDOT4
  return __builtin_amdgcn_sdot4(a, b, c, false);
#else
  return c + (int)(signed char)(a)     * (int)(signed char)(b)
           + (int)(signed char)(a>>8)  * (int)(signed char)(b>>8)
           + (int)(signed char)(a>>16) * (int)(signed char)(b>>16)
           + (int)(signed char)(a>>24) * (int)(signed char)(b>>24);
#endif
}
__device__ __forceinline__ int dot16(uint4 h, uint4 w, int acc){
  acc = sdot4i((int)h.x, (int)w.x, acc);
  acc = sdot4i((int)h.y, (int)w.y, acc);
  acc = sdot4i((int)h.z, (int)w.z, acc);
  acc = sdot4i((int)h.w, (int)w.w, acc);
  return acc;
}

// ---------------------------------------------------------------------------
// K0a: per-column absmax scale for hl-part of Wr (rows 0..255).
// ---------------------------------------------------------------------------
__global__ __launch_bounds__(64) void k0a_scale(const float* __restrict__ Wr,
    float* __restrict__ scales){
  const int n = blockIdx.x, t = threadIdx.x;
  float m = 0.f;
  #pragma unroll
  for (int j=0;j<4;j++) m = fmaxf(m, fabsf(Wr[(size_t)(t+64*j)*N5_ + n]));
  #pragma unroll
  for (int off=32; off; off>>=1) m = fmaxf(m, __shfl_xor(m, off, 64));
  if (t==0) scales[n] = fmaxf(m, 1e-20f) * (1.f/127.f);
}

// ---------------------------------------------------------------------------
// K0b: quantize hl-part of Wr to int8 uint4-planes (5 gates x 16 planes x 256).
// ---------------------------------------------------------------------------
__global__ __launch_bounds__(256) void k0b_quant(const float* __restrict__ Wr,
    const float* __restrict__ scales, uint4* __restrict__ W4){
  int idx = blockIdx.x*256 + threadIdx.x;
  if (idx >= 20480) return;
  const int g  = idx >> 12;
  const int r  = idx & 4095;
  const int c4 = r >> 8;
  const int np = r & 255;
  const int col = g*256 + np;
  const float inv = 1.f / scales[col];
  unsigned int d[4];
  #pragma unroll
  for (int dd=0; dd<4; dd++){
    unsigned int acc = 0;
    #pragma unroll
    for (int j=0;j<4;j++){
      const int k = 16*c4 + 4*dd + j;
      float w = Wr[(size_t)k*N5_ + col];
      int q = (int)rintf(w * inv);
      q = q > 127 ? 127 : (q < -127 ? -127 : q);
      acc |= ((unsigned int)(q & 255)) << (8*j);
    }
    d[dd] = acc;
  }
  uint4 v; v.x=d[0]; v.y=d[1]; v.z=d[2]; v.w=d[3];
  W4[idx] = v;
}

// ---------------------------------------------------------------------------
// K1: fused projection GEMM (unchanged).
// ---------------------------------------------------------------------------
__global__ __launch_bounds__(256) void k1_proj(
    const float* __restrict__ x, const float* __restrict__ Wp, const float* __restrict__ bp,
    const float* __restrict__ Wg, const float* __restrict__ bg,
    _Float16* __restrict__ h2, _Float16* __restrict__ c2){
  __shared__ __align__(16) _Float16 As [64*32];
  __shared__ __align__(16) _Float16 BsP[64*32];
  __shared__ __align__(16) _Float16 BsG[64*32];
  const int tid = threadIdx.x;
  const int row0 = blockIdx.x * 64;
  const int n0   = blockIdx.y * 64;
  const int wave = tid >> 6, lane = tid & 63;
  const int ml = lane & 15, quad = lane >> 4;
  float4_t accP[4], accG[4];
  #pragma unroll
  for (int i=0;i<4;i++){ accP[i]=(float4_t)(0.f); accG[i]=(float4_t)(0.f); }
  const int ar = tid >> 2, ak = (tid & 3) * 8;
  const int bk = tid >> 3, bn = (tid & 7) * 8;
  for (int kk = 0; kk < E_; kk += 32){
    __syncthreads();
    {
      const float* src = x + (size_t)(row0 + ar)*E_ + kk + ak;
      float v[8];
      #pragma unroll
      for (int q=0;q<2;q++){
        if (kk + ak + q*4 + 4 <= E_){
          float4_t f = *(const float4_t*)(src + q*4);
          v[q*4+0]=f.x; v[q*4+1]=f.y; v[q*4+2]=f.z; v[q*4+3]=f.w;
        } else {
          #pragma unroll
          for (int j=0;j<4;j++){ int kg = kk+ak+q*4+j; v[q*4+j] = (kg<E_) ? src[q*4+j] : 0.f; }
        }
      }
      #pragma unroll
      for (int j=0;j<8;j++) As[ar*32 + ak + j] = (_Float16)v[j];
    }
    {
      const int kg = kk + bk;
      if (kg < E_){
        const float* sp_ = Wp + (size_t)kg*H_ + n0 + bn;
        const float* sg_ = Wg + (size_t)kg*H_ + n0 + bn;
        float4_t p0 = *(const float4_t*)sp_, p1 = *(const float4_t*)(sp_+4);
        float4_t g0 = *(const float4_t*)sg_, g1 = *(const float4_t*)(sg_+4);
        float pv[8]={p0.x,p0.y,p0.z,p0.w,p1.x,p1.y,p1.z,p1.w};
        float gv[8]={g0.x,g0.y,g0.z,g0.w,g1.x,g1.y,g1.z,g1.w};
        #pragma unroll
        for (int j=0;j<8;j++){ BsP[(bn+j)*32+bk]=(_Float16)pv[j]; BsG[(bn+j)*32+bk]=(_Float16)gv[j]; }
      } else {
        #pragma unroll
        for (int j=0;j<8;j++){ BsP[(bn+j)*32+bk]=(_Float16)0.f; BsG[(bn+j)*32+bk]=(_Float16)0.f; }
      }
    }
    __syncthreads();
    half8_t a = *(const half8_t*)&As[(wave*16 + ml)*32 + quad*8];
    #pragma unroll
    for (int nt=0; nt<4; nt++){
      half8_t b1 = *(const half8_t*)&BsP[(nt*16 + ml)*32 + quad*8];
      accP[nt] = __builtin_amdgcn_mfma_f32_16x16x32_f16(a, b1, accP[nt], 0,0,0);
      half8_t b2 = *(const half8_t*)&BsG[(nt*16 + ml)*32 + quad*8];
      accG[nt] = __builtin_amdgcn_mfma_f32_16x16x32_f16(a, b2, accG[nt], 0,0,0);
    }
  }
  #pragma unroll
  for (int nt=0; nt<4; nt++){
    #pragma unroll
    for (int r=0;r<4;r++){
      int row = row0 + wave*16 + quad*4 + r;
      int col = n0 + nt*16 + ml;
      float c = accP[nt][r] + bp[col];
      float g = accG[nt][r] + bg[col];
      float h = sigm(g) * tanhf(c);
      size_t o = (size_t)row*H_ + col;
      c2[o] = (_Float16)c;
      h2[o] = (_Float16)h;
    }
  }
}

// ---------------------------------------------------------------------------
// K2: R = h_buf @ Wr[256:512,:] + br -> f16 R2 (unchanged)
// ---------------------------------------------------------------------------
__global__ __launch_bounds__(256) void k2_rproj(
    const _Float16* __restrict__ h2, const float* __restrict__ Wr, const float* __restrict__ br,
    _Float16* __restrict__ R2){
  __shared__ __align__(16) _Float16 As[64*32];
  __shared__ __align__(16) _Float16 Bs[64*32];
  const int tid = threadIdx.x;
  const int row0 = blockIdx.x*64, n0 = blockIdx.y*64;
  const int wave = tid>>6, lane = tid&63, ml = lane&15, quad = lane>>4;
  float4_t acc[4];
  #pragma unroll
  for (int i=0;i<4;i++) acc[i]=(float4_t)(0.f);
  const int ar = tid>>2, ak = (tid&3)*8;
  const int bk = tid>>3, bn = (tid&7)*8;
  for (int kk=0; kk<H_; kk+=32){
    __syncthreads();
    *(half8_t*)&As[ar*32+ak] = *(const half8_t*)(h2 + (size_t)(row0+ar)*H_ + kk + ak);
    {
      const float* src = Wr + (size_t)(256 + kk + bk)*N5_ + n0 + bn;
      float4_t f0 = *(const float4_t*)src, f1 = *(const float4_t*)(src+4);
      float v[8]={f0.x,f0.y,f0.z,f0.w,f1.x,f1.y,f1.z,f1.w};
      #pragma unroll
      for (int j=0;j<8;j++) Bs[(bn+j)*32+bk] = (_Float16)v[j];
    }
    __syncthreads();
    half8_t a = *(const half8_t*)&As[(wave*16+ml)*32 + quad*8];
    #pragma unroll
    for (int nt=0; nt<4; nt++){
      half8_t b8 = *(const half8_t*)&Bs[(nt*16+ml)*32 + quad*8];
      acc[nt] = __builtin_amdgcn_mfma_f32_16x16x32_f16(a, b8, acc[nt], 0,0,0);
    }
  }
  #pragma unroll
  for (int nt=0; nt<4; nt++){
    #pragma unroll
    for (int r=0;r<4;r++){
      int row = row0 + wave*16 + quad*4 + r;
      int col = n0 + nt*16 + ml;
      R2[(size_t)row*N5_ + col] = (_Float16)(acc[nt][r] + br[col]);
    }
  }
}

// ---------------------------------------------------------------------------
// K3 v5: int8 scan with AGPR-PINNED resident weights.
// Gates i,fl,fr: 192 dwords pinned in AGPRs via v_accvgpr_write/read inline
// asm (AGPR class is uncontended — no MFMA here — so the allocator cannot
// profitably spill them). Gate g: LDS planes. Gate o: L2 stream, pipelined.
// ---------------------------------------------------------------------------
#define K3_LDS_BYTES 84256

#define C16(X) X(0) X(1) X(2) X(3) X(4) X(5) X(6) X(7) X(8) X(9) X(10) X(11) \
  X(12) X(13) X(14) X(15)

#define AW(dst, src) asm volatile("v_accvgpr_write_b32 %0, %1" : "=a"(dst) : "v"(src));
#define AR(dst, src) asm volatile("v_accvgpr_read_b32 %0, %1" : "=v"(dst) : "a"(src));

#define DECLW(c) int iA##c##x, iA##c##y, iA##c##z, iA##c##w, \
                     iB##c##x, iB##c##y, iB##c##z, iB##c##w, \
                     iC##c##x, iC##c##y, iC##c##z, iC##c##w;

#define LOADW(c) { uint4 t0 = P0[(c)*256], t1 = P1[(c)*256], t2 = P2[(c)*256]; \
  AW(iA##c##x, t0.x) AW(iA##c##y, t0.y) AW(iA##c##z, t0.z) AW(iA##c##w, t0.w) \
  AW(iB##c##x, t1.x) AW(iB##c##y, t1.y) AW(iB##c##z, t1.z) AW(iB##c##w, t1.w) \
  AW(iC##c##x, t2.x) AW(iC##c##y, t2.y) AW(iC##c##z, t2.z) AW(iC##c##w, t2.w) }

#define DOCHUNK(c, OV) { const uint4 hv = hli4[c]; uint4 t; \
  AR(t.x, iA##c##x) AR(t.y, iA##c##y) AR(t.z, iA##c##z) AR(t.w, iA##c##w) \
  d0 = dot16(hv, t, d0); \
  AR(t.x, iB##c##x) AR(t.y, iB##c##y) AR(t.z, iB##c##z) AR(t.w, iB##c##w) \
  d1 = dot16(hv, t, d1); \
  AR(t.x, iC##c##x) AR(t.y, iC##c##y) AR(t.z, iC##c##z) AR(t.w, iC##c##w) \
  d2 = dot16(hv, t, d2); \
  const uint4 gv = wgl[(c)*256 + tid]; d3 = dot16(hv, gv, d3); \
  d4 = dot16(hv, OV, d4); }

__global__ __launch_bounds__(256, 1) void k3_scan(
    const int* __restrict__ trans, const _Float16* __restrict__ h2, const _Float16* __restrict__ c2,
    const _Float16* __restrict__ R2, const uint4* __restrict__ W4,
    const float* __restrict__ scales, const float* __restrict__ Wr,
    const float* __restrict__ br, float* __restrict__ out){
  extern __shared__ char smem[];
  uint4* wgl          = (uint4*)smem;
  float* sh_          = (float*)(smem + 65536);
  float* sc_          = (float*)(smem + 73728);
  unsigned int* hli   = (unsigned int*)(smem + 81920);
  int* tags           = (int*)(smem + 82176);
  int* trs            = (int*)(smem + 82208);
  const uint4* hli4   = (const uint4*)hli;

  const int b = blockIdx.x, tid = threadIdx.x;

  // --- prologue: pin int8 weights for gates i/fl/fr into AGPRs
  C16(DECLW)
  {
    const uint4* P0 = W4 +  0*256 + tid;
    const uint4* P1 = W4 + 16*256 + tid;
    const uint4* P2 = W4 + 32*256 + tid;
    C16(LOADW)
  }
  { // g-gate planes -> LDS
    const uint4* P3 = W4 + 48*256 + tid;
    #pragma unroll
    for (int c=0;c<16;c++) wgl[c*256 + tid] = P3[c*256];
  }
  const uint4* oP = W4 + 64*256 + tid;   // o-gate stream base (L2-hot)

  const float scf0 = scales[tid       ] * (1.f/127.f);
  const float scf1 = scales[tid +  256] * (1.f/127.f);
  const float scf2 = scales[tid +  512] * (1.f/127.f);
  const float scf3 = scales[tid +  768] * (1.f/127.f);
  const float scf4 = scales[tid + 1024] * (1.f/127.f);

  trs[tid] = (tid < NSTEPS) ? trans[(size_t)tid*B_ + b] : 1;
  { int j = 256 + tid; if (j < NSTEPS) trs[j] = trans[(size_t)j*B_ + b]; }
  #pragma unroll
  for (int d=0; d<DMAX; d++){ sh_[d*H_+tid]=0.f; sc_[d*H_+tid]=0.f; }
  if (tid < DMAX) tags[tid] = -1;
  __syncthreads();

  int sp = 0, bptr = T_;
  int pf_tag = -1, pf_src = -1;
  _Float16 pA=(_Float16)0.f, pB=(_Float16)0.f, pC=(_Float16)0.f, pD=(_Float16)0.f, pE=(_Float16)0.f;
  _Float16 ph=(_Float16)0.f, pc_=(_Float16)0.f;

  for (int step=0; step<NSTEPS; step++){
    __syncthreads();
    const int tr = trs[step];
    int just_src = -1;
    if (tr == 0){                          // ---- SHIFT
      const int nbp = bptr - 1;
      const int src = nbp > 0 ? nbp : 0;
      int slot = sp < 0 ? 0 : (sp > DMAX-1 ? DMAX-1 : sp);
      _Float16 hv_, cv_;
      if (src == pf_src){ hv_ = ph; cv_ = pc_; }
      else { const size_t o = ((size_t)b*T_ + src)*H_ + tid; hv_ = h2[o]; cv_ = c2[o]; }
      sh_[slot*H_+tid] = (float)hv_;
      sc_[slot*H_+tid] = (float)cv_;
      if (tid == 0) tags[slot] = src;
      sp += 1; bptr = nbp; just_src = src;
    } else {                               // ---- REDUCE
      int ir = sp-1 > 0 ? sp-1 : 0;
      int il = sp-2 > 0 ? sp-2 : 0;
      ir = ir > DMAX-1 ? DMAX-1 : ir;
      il = il > DMAX-1 ? DMAX-1 : il;
      if (tid < 64){                       // pack hl -> int8 (|h|<1)
        const float* hp = &sh_[il*H_ + tid*4];
        int q0 = (int)rintf(hp[0]*127.f), q1 = (int)rintf(hp[1]*127.f);
        int q2 = (int)rintf(hp[2]*127.f), q3 = (int)rintf(hp[3]*127.f);
        hli[tid] = (unsigned int)((q0&255) | ((q1&255)<<8) | ((q2&255)<<16) | ((q3&255)<<24));
      }
      const int tg   = tags[ir];
      const float cl = sc_[il*H_+tid];
      const float cr = sc_[ir*H_+tid];
      __syncthreads();
      float a0,a1,a2,a3,a4;
      if (tg >= 0 && tg == pf_tag){
        a0=(float)pA; a1=(float)pB; a2=(float)pC; a3=(float)pD; a4=(float)pE;
      } else if (tg >= 0){
        const _Float16* rr = R2 + ((size_t)b*T_ + tg)*N5_ + tid;
        a0=(float)rr[0]; a1=(float)rr[256]; a2=(float)rr[512]; a3=(float)rr[768]; a4=(float)rr[1024];
      } else {
        a0=br[tid]; a1=br[tid+256]; a2=br[tid+512]; a3=br[tid+768]; a4=br[tid+1024];
      }
      int d0=0,d1=0,d2=0,d3=0,d4=0;
      {
        uint4 o0=oP[0*256], o1=oP[1*256], o2=oP[2*256], o3=oP[3*256];
        DOCHUNK(0,o0)  o0=oP[ 4*256];
        DOCHUNK(1,o1)  o1=oP[ 5*256];
        DOCHUNK(2,o2)  o2=oP[ 6*256];
        DOCHUNK(3,o3)  o3=oP[ 7*256];
        DOCHUNK(4,o0)  o0=oP[ 8*256];
        DOCHUNK(5,o1)  o1=oP[ 9*256];
        DOCHUNK(6,o2)  o2=oP[10*256];
        DOCHUNK(7,o3)  o3=oP[11*256];
        DOCHUNK(8,o0)  o0=oP[12*256];
        DOCHUNK(9,o1)  o1=oP[13*256];
        DOCHUNK(10,o2) o2=oP[14*256];
        DOCHUNK(11,o3) o3=oP[15*256];
        DOCHUNK(12,o0)
        DOCHUNK(13,o1)
        DOCHUNK(14,o2)
        DOCHUNK(15,o3)
      }
      a0 += scf0*(float)d0; a1 += scf1*(float)d1; a2 += scf2*(float)d2;
      a3 += scf3*(float)d3; a4 += scf4*(float)d4;
      if (tg < 0){                         // cold general fallback (never taken here)
        for (int k=0; k<H_; k++){
          const float hrk = sh_[ir*H_+k];
          const float* wr = Wr + (size_t)(256+k)*N5_ + tid;
          a0 += hrk*wr[0]; a1 += hrk*wr[256]; a2 += hrk*wr[512];
          a3 += hrk*wr[768]; a4 += hrk*wr[1024];
        }
        __syncthreads();                   // tg block-uniform -> safe
      }
      const float cnew = sigm(a1)*cl + sigm(a2)*cr + sigm(a0)*tanhf(a3);
      const float hnew = sigm(a4)*tanhf(cnew);
      sh_[il*H_+tid] = hnew;
      sc_[il*H_+tid] = cnew;
      if (tid == 0) tags[il] = -1;
      sp -= 1;
    }
    // ---- depth-1 prefetch for the NEXT step
    if (step+1 < NSTEPS){
      const int ntr = trs[step+1];
      if (ntr == 0){
        int ns = bptr - 1; if (ns < 0) ns = 0;
        const size_t o = ((size_t)b*T_ + ns)*H_ + tid;
        ph = h2[o]; pc_ = c2[o]; pf_src = ns;
      } else if (just_src >= 0){
        const _Float16* rr = R2 + ((size_t)b*T_ + just_src)*N5_ + tid;
        pA=rr[0]; pB=rr[256]; pC=rr[512]; pD=rr[768]; pE=rr[1024];
        pf_tag = just_src;
      }
    }
  }
  __syncthreads();
  int fs = sp-1 > 0 ? sp-1 : 0;
  fs = fs > DMAX-1 ? DMAX-1 : fs;
  out[(size_t)b*H_ + tid] = sh_[fs*H_+tid];
}

// ---------------------------------------------------------------------------
// Workspace layout (bytes):
//   h2     @ 0          : 16,777,216
//   c2     @ 16777216   : 16,777,216
//   R2     @ 33554432   : 83,886,080
//   W4     @ 117440512  : 327,680
//   scales @ 117768192  : 5,120
// ---------------------------------------------------------------------------
extern "C" void kernel_launch(void* const* d_in, const int* in_sizes, int n_in,
                              void* d_out, int out_size, void* d_ws, size_t ws_size,
                              hipStream_t stream){
  const float* x    = (const float*)d_in[0];
  const int*   trn  = (const int*)  d_in[1];
  const float* Wp   = (const float*)d_in[2];
  const float* bp   = (const float*)d_in[3];
  const float* Wg   = (const float*)d_in[4];
  const float* bg   = (const float*)d_in[5];
  const float* Wr   = (const float*)d_in[6];
  const float* br   = (const float*)d_in[7];
  float* out = (float*)d_out;
  char* w = (char*)d_ws;
  _Float16* h2   = (_Float16*)(w);
  _Float16* c2   = (_Float16*)(w + (size_t)16777216);
  _Float16* R2   = (_Float16*)(w + (size_t)33554432);
  uint4*    W4   = (uint4*)   (w + (size_t)117440512);
  float*    scl  = (float*)   (w + (size_t)117768192);

  hipLaunchKernelGGL(k0a_scale, dim3(1280),    dim3(64),  0, stream, Wr, scl);
  hipLaunchKernelGGL(k0b_quant, dim3(80),      dim3(256), 0, stream, Wr, scl, W4);
  hipLaunchKernelGGL(k1_proj,   dim3(512, 4),  dim3(256), 0, stream, x, Wp, bp, Wg, bg, h2, c2);
  hipLaunchKernelGGL(k2_rproj,  dim3(512, 20), dim3(256), 0, stream, h2, Wr, br, R2);
  hipLaunchKernelGGL(k3_scan,   dim3(128),     dim3(256), K3_LDS_BYTES, stream, trn, h2, c2, R2, W4, scl, Wr, br, out);
}

// Round 7
// 960.268 us; speedup vs baseline: 2.1479x; 1.0455x over previous
//
#include <hip/hip_runtime.h>
#include <hip/hip_fp16.h>
#include <math.h>

#define B_ 128
#define T_ 256
#define E_ 300
#define H_ 256
#define N5_ 1280
#define NSTEPS 511
#define DMAX 8

typedef _Float16 half8_t __attribute__((ext_vector_type(8)));
typedef float float4_t __attribute__((ext_vector_type(4)));
typedef int i4v __attribute__((ext_vector_type(4)));
typedef unsigned int u4v __attribute__((ext_vector_type(4)));

__device__ __forceinline__ float sigm(float x){ return 1.f/(1.f + expf(-x)); }

// ---------------------------------------------------------------------------
// K0a: per-column absmax scale for hl-part of Wr (rows 0..255).
// ---------------------------------------------------------------------------
__global__ __launch_bounds__(64) void k0a_scale(const float* __restrict__ Wr,
    float* __restrict__ scales){
  const int n = blockIdx.x, t = threadIdx.x;
  float m = 0.f;
  #pragma unroll
  for (int j=0;j<4;j++) m = fmaxf(m, fabsf(Wr[(size_t)(t+64*j)*N5_ + n]));
  #pragma unroll
  for (int off=32; off; off>>=1) m = fmaxf(m, __shfl_xor(m, off, 64));
  if (t==0) scales[n] = fmaxf(m, 1e-20f) * (1.f/127.f);
}

// ---------------------------------------------------------------------------
// K0b: quantize hl-part of Wr (rows 0..255) into int8 MFMA B-fragments.
// Frag f = w*80 + g*16 + cg*4 + kc ; lane l holds col = g*256+w*64+cg*16+(l&15),
// dword r byte j -> k = kc*64 + (l>>4)*16 + r*4 + j.
// ---------------------------------------------------------------------------
__global__ __launch_bounds__(256) void k0b_quant(const float* __restrict__ Wr,
    const float* __restrict__ scales, uint4* __restrict__ W4){
  int idx = blockIdx.x*256 + threadIdx.x;
  if (idx >= 20480) return;
  const int f    = idx >> 6;
  const int lane = idx & 63;
  const int w    = f / 80;
  const int r80  = f - w*80;
  const int g    = r80 >> 4;
  const int cg   = (r80 >> 2) & 3;
  const int kc   = r80 & 3;
  const int ml   = lane & 15, quad = lane >> 4;
  const int col  = g*256 + w*64 + cg*16 + ml;
  const float inv = 1.f / scales[col];
  unsigned int d[4];
  #pragma unroll
  for (int r=0; r<4; r++){
    unsigned int acc = 0;
    #pragma unroll
    for (int j=0; j<4; j++){
      const int k = kc*64 + quad*16 + r*4 + j;
      float wv = Wr[(size_t)k*N5_ + col];
      int q = (int)rintf(wv * inv);
      q = q > 127 ? 127 : (q < -127 ? -127 : q);
      acc |= ((unsigned int)(q & 255)) << (8*j);
    }
    d[r] = acc;
  }
  uint4 v; v.x=d[0]; v.y=d[1]; v.z=d[2]; v.w=d[3];
  W4[idx] = v;
}

// ---------------------------------------------------------------------------
// K1: fused projection GEMM (unchanged).
// ---------------------------------------------------------------------------
__global__ __launch_bounds__(256) void k1_proj(
    const float* __restrict__ x, const float* __restrict__ Wp, const float* __restrict__ bp,
    const float* __restrict__ Wg, const float* __restrict__ bg,
    _Float16* __restrict__ h2, _Float16* __restrict__ c2){
  __shared__ __align__(16) _Float16 As [64*32];
  __shared__ __align__(16) _Float16 BsP[64*32];
  __shared__ __align__(16) _Float16 BsG[64*32];
  const int tid = threadIdx.x;
  const int row0 = blockIdx.x * 64;
  const int n0   = blockIdx.y * 64;
  const int wave = tid >> 6, lane = tid & 63;
  const int ml = lane & 15, quad = lane >> 4;
  float4_t accP[4], accG[4];
  #pragma unroll
  for (int i=0;i<4;i++){ accP[i]=(float4_t)(0.f); accG[i]=(float4_t)(0.f); }
  const int ar = tid >> 2, ak = (tid & 3) * 8;
  const int bk = tid >> 3, bn = (tid & 7) * 8;
  for (int kk = 0; kk < E_; kk += 32){
    __syncthreads();
    {
      const float* src = x + (size_t)(row0 + ar)*E_ + kk + ak;
      float v[8];
      #pragma unroll
      for (int q=0;q<2;q++){
        if (kk + ak + q*4 + 4 <= E_){
          float4_t f = *(const float4_t*)(src + q*4);
          v[q*4+0]=f.x; v[q*4+1]=f.y; v[q*4+2]=f.z; v[q*4+3]=f.w;
        } else {
          #pragma unroll
          for (int j=0;j<4;j++){ int kg = kk+ak+q*4+j; v[q*4+j] = (kg<E_) ? src[q*4+j] : 0.f; }
        }
      }
      #pragma unroll
      for (int j=0;j<8;j++) As[ar*32 + ak + j] = (_Float16)v[j];
    }
    {
      const int kg = kk + bk;
      if (kg < E_){
        const float* sp_ = Wp + (size_t)kg*H_ + n0 + bn;
        const float* sg_ = Wg + (size_t)kg*H_ + n0 + bn;
        float4_t p0 = *(const float4_t*)sp_, p1 = *(const float4_t*)(sp_+4);
        float4_t g0 = *(const float4_t*)sg_, g1 = *(const float4_t*)(sg_+4);
        float pv[8]={p0.x,p0.y,p0.z,p0.w,p1.x,p1.y,p1.z,p1.w};
        float gv[8]={g0.x,g0.y,g0.z,g0.w,g1.x,g1.y,g1.z,g1.w};
        #pragma unroll
        for (int j=0;j<8;j++){ BsP[(bn+j)*32+bk]=(_Float16)pv[j]; BsG[(bn+j)*32+bk]=(_Float16)gv[j]; }
      } else {
        #pragma unroll
        for (int j=0;j<8;j++){ BsP[(bn+j)*32+bk]=(_Float16)0.f; BsG[(bn+j)*32+bk]=(_Float16)0.f; }
      }
    }
    __syncthreads();
    half8_t a = *(const half8_t*)&As[(wave*16 + ml)*32 + quad*8];
    #pragma unroll
    for (int nt=0; nt<4; nt++){
      half8_t b1 = *(const half8_t*)&BsP[(nt*16 + ml)*32 + quad*8];
      accP[nt] = __builtin_amdgcn_mfma_f32_16x16x32_f16(a, b1, accP[nt], 0,0,0);
      half8_t b2 = *(const half8_t*)&BsG[(nt*16 + ml)*32 + quad*8];
      accG[nt] = __builtin_amdgcn_mfma_f32_16x16x32_f16(a, b2, accG[nt], 0,0,0);
    }
  }
  #pragma unroll
  for (int nt=0; nt<4; nt++){
    #pragma unroll
    for (int r=0;r<4;r++){
      int row = row0 + wave*16 + quad*4 + r;
      int col = n0 + nt*16 + ml;
      float c = accP[nt][r] + bp[col];
      float g = accG[nt][r] + bg[col];
      float h = sigm(g) * tanhf(c);
      size_t o = (size_t)row*H_ + col;
      c2[o] = (_Float16)c;
      h2[o] = (_Float16)h;
    }
  }
}

// ---------------------------------------------------------------------------
// K2: R = h_buf @ Wr[256:512,:] + br -> f16 R2 (unchanged)
// ---------------------------------------------------------------------------
__global__ __launch_bounds__(256) void k2_rproj(
    const _Float16* __restrict__ h2, const float* __restrict__ Wr, const float* __restrict__ br,
    _Float16* __restrict__ R2){
  __shared__ __align__(16) _Float16 As[64*32];
  __shared__ __align__(16) _Float16 Bs[64*32];
  const int tid = threadIdx.x;
  const int row0 = blockIdx.x*64, n0 = blockIdx.y*64;
  const int wave = tid>>6, lane = tid&63, ml = lane&15, quad = lane>>4;
  float4_t acc[4];
  #pragma unroll
  for (int i=0;i<4;i++) acc[i]=(float4_t)(0.f);
  const int ar = tid>>2, ak = (tid&3)*8;
  const int bk = tid>>3, bn = (tid&7)*8;
  for (int kk=0; kk<H_; kk+=32){
    __syncthreads();
    *(half8_t*)&As[ar*32+ak] = *(const half8_t*)(h2 + (size_t)(row0+ar)*H_ + kk + ak);
    {
      const float* src = Wr + (size_t)(256 + kk + bk)*N5_ + n0 + bn;
      float4_t f0 = *(const float4_t*)src, f1 = *(const float4_t*)(src+4);
      float v[8]={f0.x,f0.y,f0.z,f0.w,f1.x,f1.y,f1.z,f1.w};
      #pragma unroll
      for (int j=0;j<8;j++) Bs[(bn+j)*32+bk] = (_Float16)v[j];
    }
    __syncthreads();
    half8_t a = *(const half8_t*)&As[(wave*16+ml)*32 + quad*8];
    #pragma unroll
    for (int nt=0; nt<4; nt++){
      half8_t b8 = *(const half8_t*)&Bs[(nt*16+ml)*32 + quad*8];
      acc[nt] = __builtin_amdgcn_mfma_f32_16x16x32_f16(a, b8, acc[nt], 0,0,0);
    }
  }
  #pragma unroll
  for (int nt=0; nt<4; nt++){
    #pragma unroll
    for (int r=0;r<4;r++){
      int row = row0 + wave*16 + quad*4 + r;
      int col = n0 + nt*16 + ml;
      R2[(size_t)row*N5_ + col] = (_Float16)(acc[nt][r] + br[col]);
    }
  }
}

// ---------------------------------------------------------------------------
// K3 v7: MFMA scan with AGPR-resident weights + EXPLICIT HAZARD FENCES.
// Inline-asm MFMA bypasses compiler hazard insertion, so:
//   FENCE_IN  (s_nop 1)        : VALU zero-init -> MFMA SrcC read  (~2 cyc)
//   FENCE_OUT (s_nop 7 x2)     : MFMA D write  -> VALU read        (~16 cyc)
// Both carry the accumulators as "+v" operands so they cannot be scheduled
// around. Everything else identical to v6.
// ---------------------------------------------------------------------------
#define K3_LDS_BYTES 51488

#define FULLG(X, g) X(g,0,0) X(g,0,1) X(g,0,2) X(g,0,3) X(g,1,0) X(g,1,1) X(g,1,2) X(g,1,3) \
                    X(g,2,0) X(g,2,1) X(g,2,2) X(g,2,3) X(g,3,0) X(g,3,1) X(g,3,2) X(g,3,3)
#define PARTG(X) X(3,0,0) X(3,0,1) X(3,0,2) X(3,0,3) X(3,1,0) X(3,1,1) X(3,1,2) X(3,1,3)
#define ALLRES(X) FULLG(X,0) FULLG(X,1) FULLG(X,2) PARTG(X)
#define OLIST(X) X(0,0) X(0,1) X(0,2) X(0,3) X(1,0) X(1,1) X(1,2) X(1,3) \
                 X(2,0) X(2,1) X(2,2) X(2,3) X(3,0) X(3,1) X(3,2) X(3,3)

#define DECLF(g,cg,kc) u4v bf##g##_##cg##_##kc;
#define LOADF(g,cg,kc) bf##g##_##cg##_##kc = wb[((g)*16 + (cg)*4 + (kc))*64];
#define DECLO(cg,kc) u4v of##cg##_##kc;
#define LOADO(cg,kc) of##cg##_##kc = wb[(64 + (cg)*4 + (kc))*64];

#define MFA(ACC, AF, BF) asm volatile("v_mfma_i32_16x16x64_i8 %0, %1, %2, %0" \
    : "+v"(ACC) : "v"(AF), "a"(BF));
#define MFV(ACC, AF, BF) asm volatile("v_mfma_i32_16x16x64_i8 %0, %1, %2, %0" \
    : "+v"(ACC) : "v"(AF), "v"(BF));
#define FENCE_IN(A0,A1,A2,A3)  asm volatile("s_nop 1" : "+v"(A0), "+v"(A1), "+v"(A2), "+v"(A3));
#define FENCE_OUT(A0,A1,A2,A3) asm volatile("s_nop 7\n\ts_nop 7" : "+v"(A0), "+v"(A1), "+v"(A2), "+v"(A3));

#define GCHAIN_RES(g, DST) { \
  i4v A0={0,0,0,0}, A1={0,0,0,0}, A2={0,0,0,0}, A3={0,0,0,0}; \
  FENCE_IN(A0,A1,A2,A3) \
  MFA(A0,af0,bf##g##_0_0) MFA(A1,af0,bf##g##_1_0) MFA(A2,af0,bf##g##_2_0) MFA(A3,af0,bf##g##_3_0) \
  MFA(A0,af1,bf##g##_0_1) MFA(A1,af1,bf##g##_1_1) MFA(A2,af1,bf##g##_2_1) MFA(A3,af1,bf##g##_3_1) \
  MFA(A0,af2,bf##g##_0_2) MFA(A1,af2,bf##g##_1_2) MFA(A2,af2,bf##g##_2_2) MFA(A3,af2,bf##g##_3_2) \
  MFA(A0,af3,bf##g##_0_3) MFA(A1,af3,bf##g##_1_3) MFA(A2,af3,bf##g##_2_3) MFA(A3,af3,bf##g##_3_3) \
  FENCE_OUT(A0,A1,A2,A3) \
  DST = quad==0 ? A0.x : quad==1 ? A1.x : quad==2 ? A2.x : A3.x; }

__global__ __launch_bounds__(256, 1) void k3_scan(
    const int* __restrict__ trans, const _Float16* __restrict__ h2, const _Float16* __restrict__ c2,
    const _Float16* __restrict__ R2, const uint4* __restrict__ W4,
    const float* __restrict__ scales, const float* __restrict__ Wr,
    const float* __restrict__ br, float* __restrict__ out){
  extern __shared__ char smem[];
  u4v*  wldsG3 = (u4v*)smem;
  float* sh_   = (float*)(smem + 32768);
  float* sc_   = (float*)(smem + 40960);
  unsigned int* hli = (unsigned int*)(smem + 49152);
  int* tags    = (int*)(smem + 49408);
  int* trs     = (int*)(smem + 49440);

  const int b = blockIdx.x, tid = threadIdx.x;
  const int lane = tid & 63, w = tid >> 6;
  const int quad = (lane >> 4);

  const u4v* WB4v = (const u4v*)W4;
  const u4v* wb   = WB4v + (size_t)w*5120 + lane;

  ALLRES(DECLF)
  ALLRES(LOADF)

  #pragma unroll
  for (int t=0; t<8; t++){
    const int flat = t*256 + tid;
    const int q = flat >> 6, l2 = flat & 63;
    const int ww = q >> 3, cc = (q >> 2) & 1, kk = q & 3;
    wldsG3[flat] = WB4v[(size_t)(ww*80 + 48 + (cc+2)*4 + kk)*64 + l2];
  }
  const u4v* g3p = wldsG3 + (size_t)w*512 + lane;

  const float scf0 = scales[tid       ] * (1.f/127.f);
  const float scf1 = scales[tid +  256] * (1.f/127.f);
  const float scf2 = scales[tid +  512] * (1.f/127.f);
  const float scf3 = scales[tid +  768] * (1.f/127.f);
  const float scf4 = scales[tid + 1024] * (1.f/127.f);

  trs[tid] = (tid < NSTEPS) ? trans[(size_t)tid*B_ + b] : 1;
  { int j = 256 + tid; if (j < NSTEPS) trs[j] = trans[(size_t)j*B_ + b]; }
  #pragma unroll
  for (int d=0; d<DMAX; d++){ sh_[d*H_+tid]=0.f; sc_[d*H_+tid]=0.f; }
  if (tid < DMAX) tags[tid] = -1;
  __syncthreads();

  int sp = 0, bptr = T_;
  int pf_tag = -1, pf_src = -1;
  _Float16 pA=(_Float16)0.f, pB=(_Float16)0.f, pC=(_Float16)0.f, pD=(_Float16)0.f, pE=(_Float16)0.f;
  _Float16 ph=(_Float16)0.f, pc_=(_Float16)0.f;

  for (int step=0; step<NSTEPS; step++){
    __syncthreads();
    const int tr = trs[step];
    int just_src = -1;
    if (tr == 0){                          // ---- SHIFT
      const int nbp = bptr - 1;
      const int src = nbp > 0 ? nbp : 0;
      int slot = sp < 0 ? 0 : (sp > DMAX-1 ? DMAX-1 : sp);
      _Float16 hv_, cv_;
      if (src == pf_src){ hv_ = ph; cv_ = pc_; }
      else { const size_t o = ((size_t)b*T_ + src)*H_ + tid; hv_ = h2[o]; cv_ = c2[o]; }
      sh_[slot*H_+tid] = (float)hv_;
      sc_[slot*H_+tid] = (float)cv_;
      if (tid == 0) tags[slot] = src;
      sp += 1; bptr = nbp; just_src = src;
    } else {                               // ---- REDUCE
      int ir = sp-1 > 0 ? sp-1 : 0;
      int il = sp-2 > 0 ? sp-2 : 0;
      ir = ir > DMAX-1 ? DMAX-1 : ir;
      il = il > DMAX-1 ? DMAX-1 : il;
      if (tid < 64){                       // pack hl -> int8 (|h|<1)
        const float* hp = &sh_[il*H_ + tid*4];
        int q0 = (int)rintf(hp[0]*127.f), q1 = (int)rintf(hp[1]*127.f);
        int q2 = (int)rintf(hp[2]*127.f), q3 = (int)rintf(hp[3]*127.f);
        hli[tid] = (unsigned int)((q0&255) | ((q1&255)<<8) | ((q2&255)<<16) | ((q3&255)<<24));
      }
      const int tg   = tags[ir];
      const float cl = sc_[il*H_+tid];
      const float cr = sc_[ir*H_+tid];
      __syncthreads();

      OLIST(DECLO)
      OLIST(LOADO)
      u4v lf2_0 = g3p[(0*4+0)*64], lf2_1 = g3p[(0*4+1)*64], lf2_2 = g3p[(0*4+2)*64], lf2_3 = g3p[(0*4+3)*64];
      u4v lf3_0 = g3p[(1*4+0)*64], lf3_1 = g3p[(1*4+1)*64], lf3_2 = g3p[(1*4+2)*64], lf3_3 = g3p[(1*4+3)*64];
      const u4v af0 = *(const u4v*)&hli[ 0 + quad*4];
      const u4v af1 = *(const u4v*)&hli[16 + quad*4];
      const u4v af2 = *(const u4v*)&hli[32 + quad*4];
      const u4v af3 = *(const u4v*)&hli[48 + quad*4];

      float a0,a1,a2,a3,a4;
      if (tg >= 0 && tg == pf_tag){
        a0=(float)pA; a1=(float)pB; a2=(float)pC; a3=(float)pD; a4=(float)pE;
      } else if (tg >= 0){
        const _Float16* rr = R2 + ((size_t)b*T_ + tg)*N5_ + tid;
        a0=(float)rr[0]; a1=(float)rr[256]; a2=(float)rr[512]; a3=(float)rr[768]; a4=(float)rr[1024];
      } else {
        a0=br[tid]; a1=br[tid+256]; a2=br[tid+512]; a3=br[tid+768]; a4=br[tid+1024];
      }

      int d0,d1,d2,d3,d4;
      GCHAIN_RES(0, d0)
      GCHAIN_RES(1, d1)
      GCHAIN_RES(2, d2)
      { // gate 3: cg0,1 resident (AGPR), cg2,3 from LDS (VGPR)
        i4v A0={0,0,0,0}, A1={0,0,0,0}, A2={0,0,0,0}, A3={0,0,0,0};
        FENCE_IN(A0,A1,A2,A3)
        MFA(A0,af0,bf3_0_0) MFA(A1,af0,bf3_1_0) MFV(A2,af0,lf2_0) MFV(A3,af0,lf3_0)
        MFA(A0,af1,bf3_0_1) MFA(A1,af1,bf3_1_1) MFV(A2,af1,lf2_1) MFV(A3,af1,lf3_1)
        MFA(A0,af2,bf3_0_2) MFA(A1,af2,bf3_1_2) MFV(A2,af2,lf2_2) MFV(A3,af2,lf3_2)
        MFA(A0,af3,bf3_0_3) MFA(A1,af3,bf3_1_3) MFV(A2,af3,lf2_3) MFV(A3,af3,lf3_3)
        FENCE_OUT(A0,A1,A2,A3)
        d3 = quad==0 ? A0.x : quad==1 ? A1.x : quad==2 ? A2.x : A3.x;
      }
      { // gate 4 (o): streamed VGPR frags
        i4v A0={0,0,0,0}, A1={0,0,0,0}, A2={0,0,0,0}, A3={0,0,0,0};
        FENCE_IN(A0,A1,A2,A3)
        MFV(A0,af0,of0_0) MFV(A1,af0,of1_0) MFV(A2,af0,of2_0) MFV(A3,af0,of3_0)
        MFV(A0,af1,of0_1) MFV(A1,af1,of1_1) MFV(A2,af1,of2_1) MFV(A3,af1,of3_1)
        MFV(A0,af2,of0_2) MFV(A1,af2,of1_2) MFV(A2,af2,of2_2) MFV(A3,af2,of3_2)
        MFV(A0,af3,of0_3) MFV(A1,af3,of1_3) MFV(A2,af3,of2_3) MFV(A3,af3,of3_3)
        FENCE_OUT(A0,A1,A2,A3)
        d4 = quad==0 ? A0.x : quad==1 ? A1.x : quad==2 ? A2.x : A3.x;
      }
      a0 += scf0*(float)d0; a1 += scf1*(float)d1; a2 += scf2*(float)d2;
      a3 += scf3*(float)d3; a4 += scf4*(float)d4;

      if (tg < 0){                         // cold general fallback (never taken here)
        for (int k=0; k<H_; k++){
          const float hrk = sh_[ir*H_+k];
          const float* wr = Wr + (size_t)(256+k)*N5_ + tid;
          a0 += hrk*wr[0]; a1 += hrk*wr[256]; a2 += hrk*wr[512];
          a3 += hrk*wr[768]; a4 += hrk*wr[1024];
        }
        __syncthreads();                   // tg block-uniform -> safe
      }
      const float cnew = sigm(a1)*cl + sigm(a2)*cr + sigm(a0)*tanhf(a3);
      const float hnew = sigm(a4)*tanhf(cnew);
      sh_[il*H_+tid] = hnew;
      sc_[il*H_+tid] = cnew;
      if (tid == 0) tags[il] = -1;
      sp -= 1;
    }
    // ---- depth-1 prefetch for the NEXT step
    if (step+1 < NSTEPS){
      const int ntr = trs[step+1];
      if (ntr == 0){
        int ns = bptr - 1; if (ns < 0) ns = 0;
        const size_t o = ((size_t)b*T_ + ns)*H_ + tid;
        ph = h2[o]; pc_ = c2[o]; pf_src = ns;
      } else if (just_src >= 0){
        const _Float16* rr = R2 + ((size_t)b*T_ + just_src)*N5_ + tid;
        pA=rr[0]; pB=rr[256]; pC=rr[512]; pD=rr[768]; pE=rr[1024];
        pf_tag = just_src;
      }
    }
  }
  __syncthreads();
  int fs = sp-1 > 0 ? sp-1 : 0;
  fs = fs > DMAX-1 ? DMAX-1 : fs;
  out[(size_t)b*H_ + tid] = sh_[fs*H_+tid];
}

// ---------------------------------------------------------------------------
// Workspace layout (bytes):
//   h2     @ 0          : 16,777,216
//   c2     @ 16777216   : 16,777,216
//   R2     @ 33554432   : 83,886,080
//   W4     @ 117440512  : 327,680   (int8 MFMA B-frags, 5 gates)
//   scales @ 117768192  : 5,120
// ---------------------------------------------------------------------------
extern "C" void kernel_launch(void* const* d_in, const int* in_sizes, int n_in,
                              void* d_out, int out_size, void* d_ws, size_t ws_size,
                              hipStream_t stream){
  const float* x    = (const float*)d_in[0];
  const int*   trn  = (const int*)  d_in[1];
  const float* Wp   = (const float*)d_in[2];
  const float* bp   = (const float*)d_in[3];
  const float* Wg   = (const float*)d_in[4];
  const float* bg   = (const float*)d_in[5];
  const float* Wr   = (const float*)d_in[6];
  const float* br   = (const float*)d_in[7];
  float* out = (float*)d_out;
  char* w = (char*)d_ws;
  _Float16* h2   = (_Float16*)(w);
  _Float16* c2   = (_Float16*)(w + (size_t)16777216);
  _Float16* R2   = (_Float16*)(w + (size_t)33554432);
  uint4*    W4   = (uint4*)   (w + (size_t)117440512);
  float*    scl  = (float*)   (w + (size_t)117768192);

  hipLaunchKernelGGL(k0a_scale, dim3(1280),    dim3(64),  0, stream, Wr, scl);
  hipLaunchKernelGGL(k0b_quant, dim3(80),      dim3(256), 0, stream, Wr, scl, W4);
  hipLaunchKernelGGL(k1_proj,   dim3(512, 4),  dim3(256), 0, stream, x, Wp, bp, Wg, bg, h2, c2);
  hipLaunchKernelGGL(k2_rproj,  dim3(512, 20), dim3(256), 0, stream, h2, Wr, br, R2);
  hipLaunchKernelGGL(k3_scan,   dim3(128),     dim3(256), K3_LDS_BYTES, stream, trn, h2, c2, R2, W4, scl, Wr, br, out);
}

// Round 9
// 925.604 us; speedup vs baseline: 2.2283x; 1.0375x over previous
//
#include <hip/hip_runtime.h>
#include <hip/hip_fp16.h>
#include <math.h>

#define B_ 128
#define T_ 256
#define E_ 300
#define H_ 256
#define N5_ 1280
#define NSTEPS 511
#define DMAX 8

typedef _Float16 half8_t __attribute__((ext_vector_type(8)));
typedef float float4_t __attribute__((ext_vector_type(4)));
typedef int i4v __attribute__((ext_vector_type(4)));
typedef unsigned int u4v __attribute__((ext_vector_type(4)));

__device__ __forceinline__ float sigm(float x){ return 1.f/(1.f + expf(-x)); }

// ---------------------------------------------------------------------------
// K0a: per-column absmax scale for hl-part of Wr (rows 0..255).
// ---------------------------------------------------------------------------
__global__ __launch_bounds__(64) void k0a_scale(const float* __restrict__ Wr,
    float* __restrict__ scales){
  const int n = blockIdx.x, t = threadIdx.x;
  float m = 0.f;
  #pragma unroll
  for (int j=0;j<4;j++) m = fmaxf(m, fabsf(Wr[(size_t)(t+64*j)*N5_ + n]));
  #pragma unroll
  for (int off=32; off; off>>=1) m = fmaxf(m, __shfl_xor(m, off, 64));
  if (t==0) scales[n] = fmaxf(m, 1e-20f) * (1.f/127.f);
}

// ---------------------------------------------------------------------------
// K0b: quantize hl-part of Wr (rows 0..255) into int8 MFMA B-fragments.
// Frag f = w*80 + g*16 + cg*4 + kc ; lane l holds col = g*256+w*64+cg*16+(l&15),
// dword r byte j -> k = kc*64 + (l>>4)*16 + r*4 + j.
// ---------------------------------------------------------------------------
__global__ __launch_bounds__(256) void k0b_quant(const float* __restrict__ Wr,
    const float* __restrict__ scales, uint4* __restrict__ W4){
  int idx = blockIdx.x*256 + threadIdx.x;
  if (idx >= 20480) return;
  const int f    = idx >> 6;
  const int lane = idx & 63;
  const int w    = f / 80;
  const int r80  = f - w*80;
  const int g    = r80 >> 4;
  const int cg   = (r80 >> 2) & 3;
  const int kc   = r80 & 3;
  const int ml   = lane & 15, quad = lane >> 4;
  const int col  = g*256 + w*64 + cg*16 + ml;
  const float inv = 1.f / scales[col];
  unsigned int d[4];
  #pragma unroll
  for (int r=0; r<4; r++){
    unsigned int acc = 0;
    #pragma unroll
    for (int j=0; j<4; j++){
      const int k = kc*64 + quad*16 + r*4 + j;
      float wv = Wr[(size_t)k*N5_ + col];
      int q = (int)rintf(wv * inv);
      q = q > 127 ? 127 : (q < -127 ? -127 : q);
      acc |= ((unsigned int)(q & 255)) << (8*j);
    }
    d[r] = acc;
  }
  uint4 v; v.x=d[0]; v.y=d[1]; v.z=d[2]; v.w=d[3];
  W4[idx] = v;
}

// ---------------------------------------------------------------------------
// K1: fused projection GEMM (unchanged).
// ---------------------------------------------------------------------------
__global__ __launch_bounds__(256) void k1_proj(
    const float* __restrict__ x, const float* __restrict__ Wp, const float* __restrict__ bp,
    const float* __restrict__ Wg, const float* __restrict__ bg,
    _Float16* __restrict__ h2, _Float16* __restrict__ c2){
  __shared__ __align__(16) _Float16 As [64*32];
  __shared__ __align__(16) _Float16 BsP[64*32];
  __shared__ __align__(16) _Float16 BsG[64*32];
  const int tid = threadIdx.x;
  const int row0 = blockIdx.x * 64;
  const int n0   = blockIdx.y * 64;
  const int wave = tid >> 6, lane = tid & 63;
  const int ml = lane & 15, quad = lane >> 4;
  float4_t accP[4], accG[4];
  #pragma unroll
  for (int i=0;i<4;i++){ accP[i]=(float4_t)(0.f); accG[i]=(float4_t)(0.f); }
  const int ar = tid >> 2, ak = (tid & 3) * 8;
  const int bk = tid >> 3, bn = (tid & 7) * 8;
  for (int kk = 0; kk < E_; kk += 32){
    __syncthreads();
    {
      const float* src = x + (size_t)(row0 + ar)*E_ + kk + ak;
      float v[8];
      #pragma unroll
      for (int q=0;q<2;q++){
        if (kk + ak + q*4 + 4 <= E_){
          float4_t f = *(const float4_t*)(src + q*4);
          v[q*4+0]=f.x; v[q*4+1]=f.y; v[q*4+2]=f.z; v[q*4+3]=f.w;
        } else {
          #pragma unroll
          for (int j=0;j<4;j++){ int kg = kk+ak+q*4+j; v[q*4+j] = (kg<E_) ? src[q*4+j] : 0.f; }
        }
      }
      #pragma unroll
      for (int j=0;j<8;j++) As[ar*32 + ak + j] = (_Float16)v[j];
    }
    {
      const int kg = kk + bk;
      if (kg < E_){
        const float* sp_ = Wp + (size_t)kg*H_ + n0 + bn;
        const float* sg_ = Wg + (size_t)kg*H_ + n0 + bn;
        float4_t p0 = *(const float4_t*)sp_, p1 = *(const float4_t*)(sp_+4);
        float4_t g0 = *(const float4_t*)sg_, g1 = *(const float4_t*)(sg_+4);
        float pv[8]={p0.x,p0.y,p0.z,p0.w,p1.x,p1.y,p1.z,p1.w};
        float gv[8]={g0.x,g0.y,g0.z,g0.w,g1.x,g1.y,g1.z,g1.w};
        #pragma unroll
        for (int j=0;j<8;j++){ BsP[(bn+j)*32+bk]=(_Float16)pv[j]; BsG[(bn+j)*32+bk]=(_Float16)gv[j]; }
      } else {
        #pragma unroll
        for (int j=0;j<8;j++){ BsP[(bn+j)*32+bk]=(_Float16)0.f; BsG[(bn+j)*32+bk]=(_Float16)0.f; }
      }
    }
    __syncthreads();
    half8_t a = *(const half8_t*)&As[(wave*16 + ml)*32 + quad*8];
    #pragma unroll
    for (int nt=0; nt<4; nt++){
      half8_t b1 = *(const half8_t*)&BsP[(nt*16 + ml)*32 + quad*8];
      accP[nt] = __builtin_amdgcn_mfma_f32_16x16x32_f16(a, b1, accP[nt], 0,0,0);
      half8_t b2 = *(const half8_t*)&BsG[(nt*16 + ml)*32 + quad*8];
      accG[nt] = __builtin_amdgcn_mfma_f32_16x16x32_f16(a, b2, accG[nt], 0,0,0);
    }
  }
  #pragma unroll
  for (int nt=0; nt<4; nt++){
    #pragma unroll
    for (int r=0;r<4;r++){
      int row = row0 + wave*16 + quad*4 + r;
      int col = n0 + nt*16 + ml;
      float c = accP[nt][r] + bp[col];
      float g = accG[nt][r] + bg[col];
      float h = sigm(g) * tanhf(c);
      size_t o = (size_t)row*H_ + col;
      c2[o] = (_Float16)c;
      h2[o] = (_Float16)h;
    }
  }
}

// ---------------------------------------------------------------------------
// K2: R = h_buf @ Wr[256:512,:] + br -> f16 R2 (unchanged)
// ---------------------------------------------------------------------------
__global__ __launch_bounds__(256) void k2_rproj(
    const _Float16* __restrict__ h2, const float* __restrict__ Wr, const float* __restrict__ br,
    _Float16* __restrict__ R2){
  __shared__ __align__(16) _Float16 As[64*32];
  __shared__ __align__(16) _Float16 Bs[64*32];
  const int tid = threadIdx.x;
  const int row0 = blockIdx.x*64, n0 = blockIdx.y*64;
  const int wave = tid>>6, lane = tid&63, ml = lane&15, quad = lane>>4;
  float4_t acc[4];
  #pragma unroll
  for (int i=0;i<4;i++) acc[i]=(float4_t)(0.f);
  const int ar = tid>>2, ak = (tid&3)*8;
  const int bk = tid>>3, bn = (tid&7)*8;
  for (int kk=0; kk<H_; kk+=32){
    __syncthreads();
    *(half8_t*)&As[ar*32+ak] = *(const half8_t*)(h2 + (size_t)(row0+ar)*H_ + kk + ak);
    {
      const float* src = Wr + (size_t)(256 + kk + bk)*N5_ + n0 + bn;
      float4_t f0 = *(const float4_t*)src, f1 = *(const float4_t*)(src+4);
      float v[8]={f0.x,f0.y,f0.z,f0.w,f1.x,f1.y,f1.z,f1.w};
      #pragma unroll
      for (int j=0;j<8;j++) Bs[(bn+j)*32+bk] = (_Float16)v[j];
    }
    __syncthreads();
    half8_t a = *(const half8_t*)&As[(wave*16+ml)*32 + quad*8];
    #pragma unroll
    for (int nt=0; nt<4; nt++){
      half8_t b8 = *(const half8_t*)&Bs[(nt*16+ml)*32 + quad*8];
      acc[nt] = __builtin_amdgcn_mfma_f32_16x16x32_f16(a, b8, acc[nt], 0,0,0);
    }
  }
  #pragma unroll
  for (int nt=0; nt<4; nt++){
    #pragma unroll
    for (int r=0;r<4;r++){
      int row = row0 + wave*16 + quad*4 + r;
      int col = n0 + nt*16 + ml;
      R2[(size_t)row*N5_ + col] = (_Float16)(acc[nt][r] + br[col]);
    }
  }
}

// ---------------------------------------------------------------------------
// K3 v9: MFMA scan — 240 AGPRs resident (<=256 HW cap!) + LDS for the rest.
//  - Resident: gates 0,1,2 full + gate3 cg0..2 = 60 frags = 240 AGPRs.
//  - LDS: gate3 cg3 + gate4 full = 20 frags/wave (80 KB block-wide); ds_read
//    dependencies are compiler-fenced (proven R7).
//  - int8 h-stack written at production (R8 structure); read/compute phase ->
//    barrier -> write phase. Hazard fences on zero-init and D-read kept.
// LDS layout (bytes):
//   [0,81920)        wlds  u4v[4w][20frag][64lane]  (gate3cg3 + gate4)
//   [81920,90112)    sh_   float[8][256]
//   [90112,98304)    sc_   float[8][256]
//   [98304,100352)   sI8   char[8][256] (int8 h stack; uint4 view = A-frags)
//   [100352,100384)  tags  int[8]
//   [100384,102432)  trs   int[512]
// ---------------------------------------------------------------------------
#define K3_LDS_BYTES 102432

#define FULLG(X, g) X(g,0,0) X(g,0,1) X(g,0,2) X(g,0,3) X(g,1,0) X(g,1,1) X(g,1,2) X(g,1,3) \
                    X(g,2,0) X(g,2,1) X(g,2,2) X(g,2,3) X(g,3,0) X(g,3,1) X(g,3,2) X(g,3,3)
#define G3RES(X) X(3,0,0) X(3,0,1) X(3,0,2) X(3,0,3) X(3,1,0) X(3,1,1) X(3,1,2) X(3,1,3) \
                 X(3,2,0) X(3,2,1) X(3,2,2) X(3,2,3)
#define ALLRES(X) FULLG(X,0) FULLG(X,1) FULLG(X,2) G3RES(X)
#define OLIST(X) X(0,0) X(0,1) X(0,2) X(0,3) X(1,0) X(1,1) X(1,2) X(1,3) \
                 X(2,0) X(2,1) X(2,2) X(2,3) X(3,0) X(3,1) X(3,2) X(3,3)

#define DECLF(g,cg,kc) u4v bf##g##_##cg##_##kc;
#define LOADF(g,cg,kc) bf##g##_##cg##_##kc = wb[((g)*16 + (cg)*4 + (kc))*64];
#define OL(cg,kc) const u4v of##cg##_##kc = lwb[(4 + (cg)*4 + (kc))*64];

#define MFA(ACC, AF, BF) asm volatile("v_mfma_i32_16x16x64_i8 %0, %1, %2, %0" \
    : "+v"(ACC) : "v"(AF), "a"(BF));
#define MFV(ACC, AF, BF) asm volatile("v_mfma_i32_16x16x64_i8 %0, %1, %2, %0" \
    : "+v"(ACC) : "v"(AF), "v"(BF));
#define FENCE_IN(A0,A1,A2,A3)  asm volatile("s_nop 1" : "+v"(A0), "+v"(A1), "+v"(A2), "+v"(A3));
#define FENCE_OUT(A0,A1,A2,A3) asm volatile("s_nop 7\n\ts_nop 7" : "+v"(A0), "+v"(A1), "+v"(A2), "+v"(A3));

#define GCHAIN_RES(g, DST) { \
  i4v A0={0,0,0,0}, A1={0,0,0,0}, A2={0,0,0,0}, A3={0,0,0,0}; \
  FENCE_IN(A0,A1,A2,A3) \
  MFA(A0,af0,bf##g##_0_0) MFA(A1,af0,bf##g##_1_0) MFA(A2,af0,bf##g##_2_0) MFA(A3,af0,bf##g##_3_0) \
  MFA(A0,af1,bf##g##_0_1) MFA(A1,af1,bf##g##_1_1) MFA(A2,af1,bf##g##_2_1) MFA(A3,af1,bf##g##_3_1) \
  MFA(A0,af2,bf##g##_0_2) MFA(A1,af2,bf##g##_1_2) MFA(A2,af2,bf##g##_2_2) MFA(A3,af2,bf##g##_3_2) \
  MFA(A0,af3,bf##g##_0_3) MFA(A1,af3,bf##g##_1_3) MFA(A2,af3,bf##g##_2_3) MFA(A3,af3,bf##g##_3_3) \
  FENCE_OUT(A0,A1,A2,A3) \
  DST = quad==0 ? A0.x : quad==1 ? A1.x : quad==2 ? A2.x : A3.x; }

__global__ __launch_bounds__(256, 1) void k3_scan(
    const int* __restrict__ trans, const _Float16* __restrict__ h2, const _Float16* __restrict__ c2,
    const _Float16* __restrict__ R2, const uint4* __restrict__ W4,
    const float* __restrict__ scales, const float* __restrict__ Wr,
    const float* __restrict__ br, float* __restrict__ out){
  extern __shared__ char smem[];
  u4v*  wlds   = (u4v*)smem;
  float* sh_   = (float*)(smem + 81920);
  float* sc_   = (float*)(smem + 90112);
  char*  sI8   = (char*)(smem + 98304);
  const u4v* sI4 = (const u4v*)(smem + 98304);
  int* tags    = (int*)(smem + 100352);
  int* trs     = (int*)(smem + 100384);

  const int b = blockIdx.x, tid = threadIdx.x;
  const int lane = tid & 63, w = tid >> 6;
  const int quad = (lane >> 4);

  const u4v* WB4v = (const u4v*)W4;
  const u4v* wb   = WB4v + (size_t)w*5120 + lane;

  // resident B-frags: gates 0..2 + gate3 cg0..2 (240 AGPRs, under 256 cap)
  ALLRES(DECLF)
  ALLRES(LOADF)

  // gate3 cg3 + gate4 -> LDS. W4 frags (w*80 + 60 + j), j=0..19 are exactly
  // gate3cg3(kc0..3) then gate4(cg*4+kc) — contiguous.
  #pragma unroll
  for (int t=0; t<20; t++){
    const int flat = t*256 + tid;
    const int q = flat >> 6, l2 = flat & 63;
    const int ww = q / 20, j = q % 20;
    wlds[flat] = WB4v[(size_t)(ww*80 + 60 + j)*64 + l2];
  }
  const u4v* lwb = wlds + (size_t)w*1280 + lane;   // 20 frags * 64 lanes

  const float scf0 = scales[tid       ] * (1.f/127.f);
  const float scf1 = scales[tid +  256] * (1.f/127.f);
  const float scf2 = scales[tid +  512] * (1.f/127.f);
  const float scf3 = scales[tid +  768] * (1.f/127.f);
  const float scf4 = scales[tid + 1024] * (1.f/127.f);

  trs[tid] = (tid < NSTEPS) ? trans[(size_t)tid*B_ + b] : 1;
  { int j = 256 + tid; if (j < NSTEPS) trs[j] = trans[(size_t)j*B_ + b]; }
  #pragma unroll
  for (int d=0; d<DMAX; d++){ sh_[d*H_+tid]=0.f; sc_[d*H_+tid]=0.f; sI8[d*H_+tid]=0; }
  if (tid < DMAX) tags[tid] = -1;
  __syncthreads();

  int sp = 0, bptr = T_;
  int pf_tag = -1, pf_src = -1;
  _Float16 pA=(_Float16)0.f, pB=(_Float16)0.f, pC=(_Float16)0.f, pD=(_Float16)0.f, pE=(_Float16)0.f;
  _Float16 ph=(_Float16)0.f, pc_=(_Float16)0.f;

  for (int step=0; step<NSTEPS; step++){
    __syncthreads();                         // barrier 1: prior writes visible
    const int tr = trs[step];
    int just_src = -1;
    float wh=0.f, wc=0.f; int wq=0, wslot=0;  // pending write
    if (tr == 0){                            // ---- SHIFT
      const int nbp = bptr - 1;
      const int src = nbp > 0 ? nbp : 0;
      wslot = sp < 0 ? 0 : (sp > DMAX-1 ? DMAX-1 : sp);
      _Float16 hv_, cv_;
      if (src == pf_src){ hv_ = ph; cv_ = pc_; }
      else { const size_t o = ((size_t)b*T_ + src)*H_ + tid; hv_ = h2[o]; cv_ = c2[o]; }
      wh = (float)hv_; wc = (float)cv_;
      wq = (int)rintf(wh * 127.f);
      sp += 1; bptr = nbp; just_src = src;
    } else {                                 // ---- REDUCE
      int ir = sp-1 > 0 ? sp-1 : 0;
      int il = sp-2 > 0 ? sp-2 : 0;
      ir = ir > DMAX-1 ? DMAX-1 : ir;
      il = il > DMAX-1 ? DMAX-1 : il;
      wslot = il;
      const int tg   = tags[ir];
      const float cl = sc_[il*H_+tid];
      const float cr = sc_[ir*H_+tid];
      // A-frags from int8 stack (broadcast within quad)
      const u4v af0 = sI4[il*16 +  0 + quad];
      const u4v af1 = sI4[il*16 +  4 + quad];
      const u4v af2 = sI4[il*16 +  8 + quad];
      const u4v af3 = sI4[il*16 + 12 + quad];
      // LDS weight frags (gate3 cg3 + gate4); loads overlap resident MFMAs
      const u4v lf3_0 = lwb[0*64], lf3_1 = lwb[1*64], lf3_2 = lwb[2*64], lf3_3 = lwb[3*64];
      OLIST(OL)

      float a0,a1,a2,a3,a4;
      if (tg >= 0 && tg == pf_tag){
        a0=(float)pA; a1=(float)pB; a2=(float)pC; a3=(float)pD; a4=(float)pE;
      } else if (tg >= 0){
        const _Float16* rr = R2 + ((size_t)b*T_ + tg)*N5_ + tid;
        a0=(float)rr[0]; a1=(float)rr[256]; a2=(float)rr[512]; a3=(float)rr[768]; a4=(float)rr[1024];
      } else {
        a0=br[tid]; a1=br[tid+256]; a2=br[tid+512]; a3=br[tid+768]; a4=br[tid+1024];
      }

      int d0,d1,d2,d3,d4;
      GCHAIN_RES(0, d0)
      GCHAIN_RES(1, d1)
      GCHAIN_RES(2, d2)
      { // gate 3: cg0..2 resident, cg3 from LDS
        i4v A0={0,0,0,0}, A1={0,0,0,0}, A2={0,0,0,0}, A3={0,0,0,0};
        FENCE_IN(A0,A1,A2,A3)
        MFA(A0,af0,bf3_0_0) MFA(A1,af0,bf3_1_0) MFA(A2,af0,bf3_2_0) MFV(A3,af0,lf3_0)
        MFA(A0,af1,bf3_0_1) MFA(A1,af1,bf3_1_1) MFA(A2,af1,bf3_2_1) MFV(A3,af1,lf3_1)
        MFA(A0,af2,bf3_0_2) MFA(A1,af2,bf3_1_2) MFA(A2,af2,bf3_2_2) MFV(A3,af2,lf3_2)
        MFA(A0,af3,bf3_0_3) MFA(A1,af3,bf3_1_3) MFA(A2,af3,bf3_2_3) MFV(A3,af3,lf3_3)
        FENCE_OUT(A0,A1,A2,A3)
        d3 = quad==0 ? A0.x : quad==1 ? A1.x : quad==2 ? A2.x : A3.x;
      }
      { // gate 4: all LDS frags
        i4v A0={0,0,0,0}, A1={0,0,0,0}, A2={0,0,0,0}, A3={0,0,0,0};
        FENCE_IN(A0,A1,A2,A3)
        MFV(A0,af0,of0_0) MFV(A1,af0,of1_0) MFV(A2,af0,of2_0) MFV(A3,af0,of3_0)
        MFV(A0,af1,of0_1) MFV(A1,af1,of1_1) MFV(A2,af1,of2_1) MFV(A3,af1,of3_1)
        MFV(A0,af2,of0_2) MFV(A1,af2,of1_2) MFV(A2,af2,of2_2) MFV(A3,af2,of3_2)
        MFV(A0,af3,of0_3) MFV(A1,af3,of1_3) MFV(A2,af3,of2_3) MFV(A3,af3,of3_3)
        FENCE_OUT(A0,A1,A2,A3)
        d4 = quad==0 ? A0.x : quad==1 ? A1.x : quad==2 ? A2.x : A3.x;
      }
      a0 += scf0*(float)d0; a1 += scf1*(float)d1; a2 += scf2*(float)d2;
      a3 += scf3*(float)d3; a4 += scf4*(float)d4;

      if (tg < 0){                           // cold general fallback (never taken here)
        for (int k=0; k<H_; k++){
          const float hrk = sh_[ir*H_+k];
          const float* wr = Wr + (size_t)(256+k)*N5_ + tid;
          a0 += hrk*wr[0]; a1 += hrk*wr[256]; a2 += hrk*wr[512];
          a3 += hrk*wr[768]; a4 += hrk*wr[1024];
        }
      }
      const float cnew = sigm(a1)*cl + sigm(a2)*cr + sigm(a0)*tanhf(a3);
      const float hnew = sigm(a4)*tanhf(cnew);
      wh = hnew; wc = cnew;
      wq = (int)rintf(hnew * 127.f);
      sp -= 1;
    }
    __syncthreads();                         // barrier 2: reads done -> write
    sh_[wslot*H_+tid] = wh;
    sc_[wslot*H_+tid] = wc;
    sI8[wslot*H_+tid] = (char)wq;
    if (tid == 0) tags[wslot] = (tr == 0) ? just_src : -1;
    // ---- depth-1 prefetch for the NEXT step ----
    if (step+1 < NSTEPS){
      const int ntr = trs[step+1];
      if (ntr == 0){
        int ns = bptr - 1; if (ns < 0) ns = 0;
        const size_t o = ((size_t)b*T_ + ns)*H_ + tid;
        ph = h2[o]; pc_ = c2[o]; pf_src = ns;
      } else if (just_src >= 0){
        const _Float16* rr = R2 + ((size_t)b*T_ + just_src)*N5_ + tid;
        pA=rr[0]; pB=rr[256]; pC=rr[512]; pD=rr[768]; pE=rr[1024];
        pf_tag = just_src;
      }
    }
  }
  __syncthreads();
  int fs = sp-1 > 0 ? sp-1 : 0;
  fs = fs > DMAX-1 ? DMAX-1 : fs;
  out[(size_t)b*H_ + tid] = sh_[fs*H_+tid];
}

// ---------------------------------------------------------------------------
// Workspace layout (bytes):
//   h2     @ 0          : 16,777,216
//   c2     @ 16777216   : 16,777,216
//   R2     @ 33554432   : 83,886,080
//   W4     @ 117440512  : 327,680   (int8 MFMA B-frags, 5 gates)
//   scales @ 117768192  : 5,120
// ---------------------------------------------------------------------------
extern "C" void kernel_launch(void* const* d_in, const int* in_sizes, int n_in,
                              void* d_out, int out_size, void* d_ws, size_t ws_size,
                              hipStream_t stream){
  const float* x    = (const float*)d_in[0];
  const int*   trn  = (const int*)  d_in[1];
  const float* Wp   = (const float*)d_in[2];
  const float* bp   = (const float*)d_in[3];
  const float* Wg   = (const float*)d_in[4];
  const float* bg   = (const float*)d_in[5];
  const float* Wr   = (const float*)d_in[6];
  const float* br   = (const float*)d_in[7];
  float* out = (float*)d_out;
  char* w = (char*)d_ws;
  _Float16* h2   = (_Float16*)(w);
  _Float16* c2   = (_Float16*)(w + (size_t)16777216);
  _Float16* R2   = (_Float16*)(w + (size_t)33554432);
  uint4*    W4   = (uint4*)   (w + (size_t)117440512);
  float*    scl  = (float*)   (w + (size_t)117768192);

  hipLaunchKernelGGL(k0a_scale, dim3(1280),    dim3(64),  0, stream, Wr, scl);
  hipLaunchKernelGGL(k0b_quant, dim3(80),      dim3(256), 0, stream, Wr, scl, W4);
  hipLaunchKernelGGL(k1_proj,   dim3(512, 4),  dim3(256), 0, stream, x, Wp, bp, Wg, bg, h2, c2);
  hipLaunchKernelGGL(k2_rproj,  dim3(512, 20), dim3(256), 0, stream, h2, Wr, br, R2);
  hipLaunchKernelGGL(k3_scan,   dim3(128),     dim3(256), K3_LDS_BYTES, stream, trn, h2, c2, R2, W4, scl, Wr, br, out);
}